// Round 12
// baseline (396.355 us; speedup 1.0000x reference)
//
#include <hip/hip_runtime.h>
#include <hip/hip_bf16.h>

#define N_NODES 100000
#define H_DIM 64
#define OUT_DIM 32
#define N_RELS 64
#define N_BASES 16
#define N_EDGES 1600000

typedef __attribute__((ext_vector_type(8))) short short8;
typedef __attribute__((ext_vector_type(4))) float f32x4;

__device__ __forceinline__ unsigned short f2bf(float f) {
    unsigned int u = __float_as_uint(f);
    u = (u + 0x7FFFu + ((u >> 16) & 1u)) >> 16;
    return (unsigned short)u;
}
__device__ __forceinline__ float bf2f(unsigned short u) {
    return __uint_as_float(((unsigned int)u) << 16);
}
__device__ __forceinline__ float shfl_f(float v, int l) {
    return __shfl(v, l, 64);
}
__device__ __forceinline__ int shfl_i(int v, int l) {
    return __shfl(v, l, 64);
}

// ---------- W_r = sum_b c[r,b] * V[b], bf16, pre-swizzled into MFMA B-fragments.
__global__ void build_w_swz(const float* __restrict__ V1, const float* __restrict__ c1,
                            const float* __restrict__ V2, const float* __restrict__ c2,
                            unsigned short* __restrict__ W1s, unsigned short* __restrict__ W2s) {
    int idx = blockIdx.x * blockDim.x + threadIdx.x;
    const int n1 = N_RELS * 4096;
    const int n2 = N_RELS * 2048;
    if (idx < n1) {
        int r = idx >> 12;
        int f = idx & 4095;
        int nb = f >> 10, kb = (f >> 9) & 1, s = f & 511;
        int lane = s >> 3, j = s & 7;
        int k = 32 * kb + 8 * (lane >> 4) + j;
        int col = ((nb >> 1) << 5) + 2 * (lane & 15) + (nb & 1);
        float acc = 0.f;
        #pragma unroll
        for (int b = 0; b < N_BASES; b++)
            acc += c1[r * N_BASES + b] * V1[(b * 64 + k) * 64 + col];
        W1s[idx] = f2bf(acc);
    } else if (idx < n1 + n2) {
        int t = idx - n1;
        int r = t >> 11;
        int f = t & 2047;
        int nb = f >> 10, kb = (f >> 9) & 1, s = f & 511;
        int lane = s >> 3, j = s & 7;
        int k = 32 * kb + 8 * (lane >> 4) + j;
        int col = 2 * (lane & 15) + nb;
        float acc = 0.f;
        #pragma unroll
        for (int b = 0; b < N_BASES; b++)
            acc += c2[r * N_BASES + b] * V2[(b * 64 + k) * 32 + col];
        W2s[t] = f2bf(acc);
    }
}

// ---------- fp32 -> bf16 table conversion ----------
__global__ void cvt_bf16_kernel(const float* __restrict__ in,
                                unsigned short* __restrict__ outp, int n4) {
    int i = blockIdx.x * blockDim.x + threadIdx.x;
    if (i < n4) {
        float4 v = ((const float4*)in)[i];
        ushort4 o;
        o.x = f2bf(v.x); o.y = f2bf(v.y); o.z = f2bf(v.z); o.w = f2bf(v.w);
        ((ushort4*)outp)[i] = o;
    }
}

// ---------- fused: etype histogram + 8-way sub-counter dst-rank ----------
// rank[e] = (localRank_within(dst,sub) << 3) | sub, sub = tid&7.
// 8-way sub-counters cut same-address atomic chains from ~16 to ~2 deep.
__global__ void hist_rank8(const int* __restrict__ etype, const int* __restrict__ dst,
                           int* __restrict__ counts, int* __restrict__ dcnt8,
                           int* __restrict__ rank) {
    __shared__ int lbin[N_RELS];
    for (int i = threadIdx.x; i < N_RELS; i += blockDim.x) lbin[i] = 0;
    __syncthreads();
    const int sub = threadIdx.x & 7;
    for (int e = blockIdx.x * blockDim.x + threadIdx.x; e < N_EDGES;
         e += gridDim.x * blockDim.x) {
        atomicAdd(&lbin[etype[e]], 1);
        int lr = atomicAdd(&dcnt8[dst[e] * 8 + sub], 1);
        rank[e] = (lr << 3) | sub;
    }
    __syncthreads();
    for (int i = threadIdx.x; i < N_RELS; i += blockDim.x)
        if (lbin[i]) atomicAdd(&counts[i], lbin[i]);
}

// ---------- plain etype histogram (Path B) ----------
__global__ void hist_kernel(const int* __restrict__ etype, int* __restrict__ counts) {
    __shared__ int lbin[N_RELS];
    for (int i = threadIdx.x; i < N_RELS; i += blockDim.x) lbin[i] = 0;
    __syncthreads();
    for (int e = blockIdx.x * blockDim.x + threadIdx.x; e < N_EDGES;
         e += gridDim.x * blockDim.x)
        atomicAdd(&lbin[etype[e]], 1);
    __syncthreads();
    for (int i = threadIdx.x; i < N_RELS; i += blockDim.x)
        if (lbin[i]) atomicAdd(&counts[i], lbin[i]);
}

// ---------- per-node exclusive scan of the 8 sub-counters (in place) ----------
// dcnt8[n][k] becomes prefix; dcnt[n] = total.
__global__ void sub_scan(int* __restrict__ dcnt8, int* __restrict__ dcnt) {
    int n = blockIdx.x * blockDim.x + threadIdx.x;
    if (n < N_NODES) {
        int s = 0;
        #pragma unroll
        for (int k = 0; k < 8; k++) {
            int v = dcnt8[n * 8 + k];
            dcnt8[n * 8 + k] = s;
            s += v;
        }
        dcnt[n] = s;
    }
}

// ---------- exclusive scan (nbins) with 64-alignment padding ----------
__global__ void scan_kernel(const int* __restrict__ counts, int* __restrict__ offs,
                            int* __restrict__ cursor, int nbins) {
    if (threadIdx.x == 0 && blockIdx.x == 0) {
        int L = 0;
        for (int r = 0; r < nbins; r++) {
            offs[r] = L;
            cursor[r] = L;
            L += (counts[r] + 63) & ~63;
        }
        offs[nbins] = L;
    }
}

// ---------- hierarchical scan over 100K dst bins ----------
__global__ void __launch_bounds__(1024) scan_a(const int* __restrict__ dcnt,
                                               int* __restrict__ nloc,
                                               int* __restrict__ bsum) {
    __shared__ int ps[1024];
    int t = threadIdx.x;
    int i = blockIdx.x * 1024 + t;
    int v = (i < N_NODES) ? dcnt[i] : 0;
    ps[t] = v;
    __syncthreads();
    int x = v;
    for (int off = 1; off < 1024; off <<= 1) {
        int y = (t >= off) ? ps[t - off] : 0;
        __syncthreads();
        x += y;
        ps[t] = x;
        __syncthreads();
    }
    if (i < N_NODES) nloc[i] = x - v;
    if (t == 1023) bsum[blockIdx.x] = x;
}

__global__ void scan_b(int* __restrict__ bsum, int nb) {
    if (threadIdx.x == 0 && blockIdx.x == 0) {
        int s = 0;
        for (int i = 0; i < nb; i++) { int t = bsum[i]; bsum[i] = s; s += t; }
        bsum[nb] = s;
    }
}

__global__ void __launch_bounds__(1024) scan_c(const int* __restrict__ nloc,
                                               const int* __restrict__ bsum,
                                               int* __restrict__ noff) {
    int t = threadIdx.x;
    int i = blockIdx.x * 1024 + t;
    if (i < N_NODES) noff[i] = nloc[i] + bsum[blockIdx.x];
    if (i == 0) noff[N_NODES] = bsum[(N_NODES + 1023) / 1024];
}

// ---------- 64-bucket scatter: perm-ordered metadata, NO atomic returns ----------
// slot = noff[dst] + dcnt8[dst*8+sub] + localRank  (all loads L2-resident).
__global__ void __launch_bounds__(256) scatter_big(
    const int* __restrict__ etype, const int* __restrict__ src,
    const int* __restrict__ dst, const float* __restrict__ norm,
    const int* __restrict__ rank, const int* __restrict__ noff,
    const int* __restrict__ dcnt8,
    int* __restrict__ cursor, int2* __restrict__ ssP, float* __restrict__ normP) {
    __shared__ int lbin[N_RELS];
    __shared__ int lbase[N_RELS];
    const int base = blockIdx.x * 2048;
    for (int i = threadIdx.x; i < N_RELS; i += 256) lbin[i] = 0;
    __syncthreads();
    int rr[8], lp[8];
    #pragma unroll
    for (int k = 0; k < 8; k++) {
        int e = base + k * 256 + threadIdx.x;
        rr[k] = -1;
        if (e < N_EDGES) {
            rr[k] = etype[e];
            lp[k] = atomicAdd(&lbin[rr[k]], 1);
        }
    }
    __syncthreads();
    for (int i = threadIdx.x; i < N_RELS; i += 256)
        lbase[i] = lbin[i] ? atomicAdd(&cursor[i], lbin[i]) : 0;
    __syncthreads();
    #pragma unroll
    for (int k = 0; k < 8; k++) {
        int e = base + k * 256 + threadIdx.x;
        if (rr[k] >= 0) {
            int pos = lbase[rr[k]] + lp[k];
            int d = dst[e];
            int rk = rank[e];
            int slot = noff[d] + dcnt8[d * 8 + (rk & 7)] + (rk >> 3);
            ssP[pos] = make_int2(src[e], slot);
            normP[pos] = norm[e];
        }
    }
}

// ---------- plain rel-bucket scatter (Path B) ----------
__global__ void scatter_kernel(const int* __restrict__ etype, int* __restrict__ cursor,
                               int* __restrict__ perm) {
    __shared__ int lbin[N_RELS];
    __shared__ int lbase[N_RELS];
    const int nChunks = (N_EDGES + 255) >> 8;
    for (int chunk = blockIdx.x; chunk < nChunks; chunk += gridDim.x) {
        for (int i = threadIdx.x; i < N_RELS; i += blockDim.x) lbin[i] = 0;
        __syncthreads();
        int e = chunk * 256 + threadIdx.x;
        int r = -1, lpos = 0;
        if (e < N_EDGES) {
            r = etype[e];
            lpos = atomicAdd(&lbin[r], 1);
        }
        __syncthreads();
        for (int i = threadIdx.x; i < N_RELS; i += blockDim.x)
            lbase[i] = lbin[i] ? atomicAdd(&cursor[i], lbin[i]) : 0;
        __syncthreads();
        if (e < N_EDGES) perm[lbase[r] + lpos] = e;
        __syncthreads();
    }
}

// =========================================================================
// PATH A edge kernels: 2-stage pipeline; index phase = 2 COALESCED loads
// (int2 ssP + float normP in perm order) + 1 random 128B gather.
// =========================================================================
__global__ void __launch_bounds__(256) edge1_mfmaA(
    const int2* __restrict__ ssP, const float* __restrict__ normP,
    const unsigned short* __restrict__ xb, const unsigned short* __restrict__ Ws,
    unsigned short* __restrict__ msg, const int* __restrict__ offs,
    const int* __restrict__ cnts) {
    const int lane = threadIdx.x & 63;
    const int wave = (blockIdx.x * blockDim.x + threadIdx.x) >> 6;
    const int nw = (gridDim.x * blockDim.x) >> 6;
    const int wpb = nw >> 6;
    const int r = wave / wpb;
    const int sub = wave - r * wpb;
    const int b0 = offs[r];
    const int cnt = cnts[r];
    const int ntiles = (cnt + 15) >> 4;
    const int c16 = lane & 15, kq = lane >> 4;

    const unsigned short* Wr = Ws + r * 4096 + lane * 8;
    short8 bfr[4][2];
    #pragma unroll
    for (int nb = 0; nb < 4; nb++)
        #pragma unroll
        for (int kb = 0; kb < 2; kb++)
            bfr[nb][kb] = *(const short8*)(Wr + ((nb * 2 + kb) << 9));

    int t = sub;
    if (t >= ntiles) return;

    float nnC; int slC; short8 a0, a1;
    {
        const int base = b0 + (t << 4);
        const int rem = cnt - (t << 4);
        int2 ss = ssP[base + c16];
        nnC = normP[base + c16];
        slC = ss.y;
        int sa = (c16 < rem) ? ss.x : 0;
        const unsigned short* xr = xb + sa * 64 + kq * 8;
        a0 = *(const short8*)(xr);
        a1 = *(const short8*)(xr + 32);
    }

    while (t < ntiles) {
        const int tn = t + wpb;
        float nnN = 0.f; int slN = 0; short8 a0N = a0, a1N = a1;
        if (tn < ntiles) {
            const int baseN = b0 + (tn << 4);
            const int remN = cnt - (tn << 4);
            int2 ssN = ssP[baseN + c16];
            nnN = normP[baseN + c16];
            slN = ssN.y;
            int saN = (c16 < remN) ? ssN.x : 0;
            const unsigned short* xrN = xb + saN * 64 + kq * 8;
            a0N = *(const short8*)(xrN);
            a1N = *(const short8*)(xrN + 32);
        }
        const int rem = cnt - (t << 4);
        f32x4 acc0{0.f, 0.f, 0.f, 0.f}, acc1{0.f, 0.f, 0.f, 0.f};
        f32x4 acc2{0.f, 0.f, 0.f, 0.f}, acc3{0.f, 0.f, 0.f, 0.f};
        acc0 = __builtin_amdgcn_mfma_f32_16x16x32_bf16(a0, bfr[0][0], acc0, 0, 0, 0);
        acc0 = __builtin_amdgcn_mfma_f32_16x16x32_bf16(a1, bfr[0][1], acc0, 0, 0, 0);
        acc1 = __builtin_amdgcn_mfma_f32_16x16x32_bf16(a0, bfr[1][0], acc1, 0, 0, 0);
        acc1 = __builtin_amdgcn_mfma_f32_16x16x32_bf16(a1, bfr[1][1], acc1, 0, 0, 0);
        acc2 = __builtin_amdgcn_mfma_f32_16x16x32_bf16(a0, bfr[2][0], acc2, 0, 0, 0);
        acc2 = __builtin_amdgcn_mfma_f32_16x16x32_bf16(a1, bfr[2][1], acc2, 0, 0, 0);
        acc3 = __builtin_amdgcn_mfma_f32_16x16x32_bf16(a0, bfr[3][0], acc3, 0, 0, 0);
        acc3 = __builtin_amdgcn_mfma_f32_16x16x32_bf16(a1, bfr[3][1], acc3, 0, 0, 0);
        #pragma unroll
        for (int ri = 0; ri < 4; ri++) {
            int li = kq * 4 + ri;
            bool valid = li < rem;
            float nn = shfl_f(nnC, li);
            int slot = shfl_i(slC, li);
            if (valid) {
                unsigned int p01 = (unsigned int)f2bf(acc0[ri] * nn) |
                                   ((unsigned int)f2bf(acc1[ri] * nn) << 16);
                unsigned int p23 = (unsigned int)f2bf(acc2[ri] * nn) |
                                   ((unsigned int)f2bf(acc3[ri] * nn) << 16);
                unsigned int* mp = (unsigned int*)(msg + (size_t)slot * 64);
                __builtin_nontemporal_store(p01, mp + c16);
                __builtin_nontemporal_store(p23, mp + 16 + c16);
            }
        }
        nnC = nnN; slC = slN; a0 = a0N; a1 = a1N;
        t = tn;
    }
}

__global__ void __launch_bounds__(256) edge2_mfmaA(
    const int2* __restrict__ ssP, const float* __restrict__ normP,
    const unsigned short* __restrict__ hb, const unsigned short* __restrict__ Ws,
    unsigned short* __restrict__ msg, const int* __restrict__ offs,
    const int* __restrict__ cnts) {
    const int lane = threadIdx.x & 63;
    const int wave = (blockIdx.x * blockDim.x + threadIdx.x) >> 6;
    const int nw = (gridDim.x * blockDim.x) >> 6;
    const int wpb = nw >> 6;
    const int r = wave / wpb;
    const int sub = wave - r * wpb;
    const int b0 = offs[r];
    const int cnt = cnts[r];
    const int ntiles = (cnt + 15) >> 4;
    const int c16 = lane & 15, kq = lane >> 4;

    const unsigned short* Wr = Ws + r * 2048 + lane * 8;
    short8 bfr[2][2];
    #pragma unroll
    for (int nb = 0; nb < 2; nb++)
        #pragma unroll
        for (int kb = 0; kb < 2; kb++)
            bfr[nb][kb] = *(const short8*)(Wr + ((nb * 2 + kb) << 9));

    int t = sub;
    if (t >= ntiles) return;

    float nnC; int slC; short8 a0, a1;
    {
        const int base = b0 + (t << 4);
        const int rem = cnt - (t << 4);
        int2 ss = ssP[base + c16];
        nnC = normP[base + c16];
        slC = ss.y;
        int sa = (c16 < rem) ? ss.x : 0;
        const unsigned short* xr = hb + sa * 64 + kq * 8;
        a0 = *(const short8*)(xr);
        a1 = *(const short8*)(xr + 32);
    }

    while (t < ntiles) {
        const int tn = t + wpb;
        float nnN = 0.f; int slN = 0; short8 a0N = a0, a1N = a1;
        if (tn < ntiles) {
            const int baseN = b0 + (tn << 4);
            const int remN = cnt - (tn << 4);
            int2 ssN = ssP[baseN + c16];
            nnN = normP[baseN + c16];
            slN = ssN.y;
            int saN = (c16 < remN) ? ssN.x : 0;
            const unsigned short* xrN = hb + saN * 64 + kq * 8;
            a0N = *(const short8*)(xrN);
            a1N = *(const short8*)(xrN + 32);
        }
        const int rem = cnt - (t << 4);
        f32x4 acc0{0.f, 0.f, 0.f, 0.f}, acc1{0.f, 0.f, 0.f, 0.f};
        acc0 = __builtin_amdgcn_mfma_f32_16x16x32_bf16(a0, bfr[0][0], acc0, 0, 0, 0);
        acc0 = __builtin_amdgcn_mfma_f32_16x16x32_bf16(a1, bfr[0][1], acc0, 0, 0, 0);
        acc1 = __builtin_amdgcn_mfma_f32_16x16x32_bf16(a0, bfr[1][0], acc1, 0, 0, 0);
        acc1 = __builtin_amdgcn_mfma_f32_16x16x32_bf16(a1, bfr[1][1], acc1, 0, 0, 0);
        #pragma unroll
        for (int ri = 0; ri < 4; ri++) {
            int li = kq * 4 + ri;
            bool valid = li < rem;
            float nn = shfl_f(nnC, li);
            int slot = shfl_i(slC, li);
            if (valid) {
                unsigned int p01 = (unsigned int)f2bf(acc0[ri] * nn) |
                                   ((unsigned int)f2bf(acc1[ri] * nn) << 16);
                __builtin_nontemporal_store(p01,
                    (unsigned int*)(msg + (size_t)slot * 32) + c16);
            }
        }
        nnC = nnN; slC = slN; a0 = a0N; a1 = a1N;
        t = tn;
    }
}

// ---------- segment sums (nontemporal msg reads, 4-deep ILP) ----------
__global__ void __launch_bounds__(256) segsum1(const unsigned short* __restrict__ msg,
                                               const int* __restrict__ noff,
                                               const float* __restrict__ b1,
                                               unsigned short* __restrict__ hb) {
    int v = (blockIdx.x * blockDim.x + threadIdx.x) >> 6;
    int lane = threadIdx.x & 63;
    if (v >= N_NODES) return;
    int s0 = noff[v], s1 = noff[v + 1];
    float a0 = 0.f, a1 = 0.f, a2 = 0.f, a3 = 0.f;
    int i = s0;
    for (; i + 3 < s1; i += 4) {
        a0 += bf2f(__builtin_nontemporal_load(msg + (size_t)i * 64 + lane));
        a1 += bf2f(__builtin_nontemporal_load(msg + (size_t)(i + 1) * 64 + lane));
        a2 += bf2f(__builtin_nontemporal_load(msg + (size_t)(i + 2) * 64 + lane));
        a3 += bf2f(__builtin_nontemporal_load(msg + (size_t)(i + 3) * 64 + lane));
    }
    for (; i < s1; i++)
        a0 += bf2f(__builtin_nontemporal_load(msg + (size_t)i * 64 + lane));
    float val = fmaxf((a0 + a1) + (a2 + a3) + b1[lane], 0.f);
    hb[v * 64 + lane] = f2bf(val);
}

__global__ void __launch_bounds__(256) segsum2(const unsigned short* __restrict__ msg,
                                               const int* __restrict__ noff,
                                               const float* __restrict__ b2,
                                               float* __restrict__ out) {
    int idx = blockIdx.x * blockDim.x + threadIdx.x;
    int v = idx >> 5, o = idx & 31;
    if (v >= N_NODES) return;
    int s0 = noff[v], s1 = noff[v + 1];
    float a0 = 0.f, a1 = 0.f, a2 = 0.f, a3 = 0.f;
    int i = s0;
    for (; i + 3 < s1; i += 4) {
        a0 += bf2f(__builtin_nontemporal_load(msg + (size_t)i * 32 + o));
        a1 += bf2f(__builtin_nontemporal_load(msg + (size_t)(i + 1) * 32 + o));
        a2 += bf2f(__builtin_nontemporal_load(msg + (size_t)(i + 2) * 32 + o));
        a3 += bf2f(__builtin_nontemporal_load(msg + (size_t)(i + 3) * 32 + o));
    }
    for (; i < s1; i++)
        a0 += bf2f(__builtin_nontemporal_load(msg + (size_t)i * 32 + o));
    out[v * 32 + o] = (a0 + a1) + (a2 + a3) + b2[o];
}

// =========================================================================
// PATH B: atomics fallback — used only if ws_size is too small.
// =========================================================================
__global__ void __launch_bounds__(256) edge1_mfmaB(
    const int* __restrict__ perm, const int* __restrict__ src,
    const int* __restrict__ dst, const float* __restrict__ norm,
    const unsigned short* __restrict__ xb, const unsigned short* __restrict__ Ws,
    float* __restrict__ hout, const int* __restrict__ offs) {
    const int lane = threadIdx.x & 63;
    const int wave = (blockIdx.x * blockDim.x + threadIdx.x) >> 6;
    const int nw = (gridDim.x * blockDim.x) >> 6;
    const int wpb = nw >> 6;
    const int r = wave / wpb;
    const int sub = wave - r * wpb;
    const int b0 = offs[r], b1v = offs[r + 1];
    const int ntiles = (b1v - b0) >> 4;
    const int c16 = lane & 15, kq = lane >> 4;
    const unsigned short* Wr = Ws + r * 4096 + lane * 8;
    short8 bfr[4][2];
    #pragma unroll
    for (int nb = 0; nb < 4; nb++)
        #pragma unroll
        for (int kb = 0; kb < 2; kb++)
            bfr[nb][kb] = *(const short8*)(Wr + ((nb * 2 + kb) << 9));
    for (int t = sub; t < ntiles; t += wpb) {
        const int base = b0 + (t << 4);
        int pa = perm[base + c16];
        int sa = pa < 0 ? 0 : src[pa];
        const unsigned short* xr = xb + sa * 64 + kq * 8;
        short8 a0 = *(const short8*)(xr);
        short8 a1 = *(const short8*)(xr + 32);
        f32x4 acc0{0.f, 0.f, 0.f, 0.f}, acc1{0.f, 0.f, 0.f, 0.f};
        f32x4 acc2{0.f, 0.f, 0.f, 0.f}, acc3{0.f, 0.f, 0.f, 0.f};
        acc0 = __builtin_amdgcn_mfma_f32_16x16x32_bf16(a0, bfr[0][0], acc0, 0, 0, 0);
        acc0 = __builtin_amdgcn_mfma_f32_16x16x32_bf16(a1, bfr[0][1], acc0, 0, 0, 0);
        acc1 = __builtin_amdgcn_mfma_f32_16x16x32_bf16(a0, bfr[1][0], acc1, 0, 0, 0);
        acc1 = __builtin_amdgcn_mfma_f32_16x16x32_bf16(a1, bfr[1][1], acc1, 0, 0, 0);
        acc2 = __builtin_amdgcn_mfma_f32_16x16x32_bf16(a0, bfr[2][0], acc2, 0, 0, 0);
        acc2 = __builtin_amdgcn_mfma_f32_16x16x32_bf16(a1, bfr[2][1], acc2, 0, 0, 0);
        acc3 = __builtin_amdgcn_mfma_f32_16x16x32_bf16(a0, bfr[3][0], acc3, 0, 0, 0);
        acc3 = __builtin_amdgcn_mfma_f32_16x16x32_bf16(a1, bfr[3][1], acc3, 0, 0, 0);
        #pragma unroll
        for (int ri = 0; ri < 4; ri++) {
            int pe = perm[base + kq * 4 + ri];
            float nn = 0.f;
            int d = 0;
            if (pe >= 0) { nn = norm[pe]; d = dst[pe]; }
            float* hrow = hout + d * 64;
            unsafeAtomicAdd(hrow + 2 * c16,      acc0[ri] * nn);
            unsafeAtomicAdd(hrow + 2 * c16 + 1,  acc1[ri] * nn);
            unsafeAtomicAdd(hrow + 32 + 2 * c16, acc2[ri] * nn);
            unsafeAtomicAdd(hrow + 33 + 2 * c16, acc3[ri] * nn);
        }
    }
}

__global__ void bias_relu_bf(const float* __restrict__ h, const float* __restrict__ b,
                             unsigned short* __restrict__ hb, int n4) {
    int i = blockIdx.x * blockDim.x + threadIdx.x;
    if (i < n4) {
        float4 v = ((const float4*)h)[i];
        float4 bv = ((const float4*)b)[i & 15];
        ushort4 o;
        o.x = f2bf(fmaxf(v.x + bv.x, 0.f));
        o.y = f2bf(fmaxf(v.y + bv.y, 0.f));
        o.z = f2bf(fmaxf(v.z + bv.z, 0.f));
        o.w = f2bf(fmaxf(v.w + bv.w, 0.f));
        ((ushort4*)hb)[i] = o;
    }
}

__global__ void __launch_bounds__(256) edge2_mfmaB(
    const int* __restrict__ perm, const int* __restrict__ src,
    const int* __restrict__ dst, const float* __restrict__ norm,
    const unsigned short* __restrict__ hb, const unsigned short* __restrict__ Ws,
    float* __restrict__ out, const int* __restrict__ offs) {
    const int lane = threadIdx.x & 63;
    const int wave = (blockIdx.x * blockDim.x + threadIdx.x) >> 6;
    const int nw = (gridDim.x * blockDim.x) >> 6;
    const int wpb = nw >> 6;
    const int r = wave / wpb;
    const int sub = wave - r * wpb;
    const int b0 = offs[r], b1v = offs[r + 1];
    const int ntiles = (b1v - b0) >> 4;
    const int c16 = lane & 15, kq = lane >> 4;
    const unsigned short* Wr = Ws + r * 2048 + lane * 8;
    short8 bfr[2][2];
    #pragma unroll
    for (int nb = 0; nb < 2; nb++)
        #pragma unroll
        for (int kb = 0; kb < 2; kb++)
            bfr[nb][kb] = *(const short8*)(Wr + ((nb * 2 + kb) << 9));
    for (int t = sub; t < ntiles; t += wpb) {
        const int base = b0 + (t << 4);
        int pa = perm[base + c16];
        int sa = pa < 0 ? 0 : src[pa];
        const unsigned short* xr = hb + sa * 64 + kq * 8;
        short8 a0 = *(const short8*)(xr);
        short8 a1 = *(const short8*)(xr + 32);
        f32x4 acc0{0.f, 0.f, 0.f, 0.f}, acc1{0.f, 0.f, 0.f, 0.f};
        acc0 = __builtin_amdgcn_mfma_f32_16x16x32_bf16(a0, bfr[0][0], acc0, 0, 0, 0);
        acc0 = __builtin_amdgcn_mfma_f32_16x16x32_bf16(a1, bfr[0][1], acc0, 0, 0, 0);
        acc1 = __builtin_amdgcn_mfma_f32_16x16x32_bf16(a0, bfr[1][0], acc1, 0, 0, 0);
        acc1 = __builtin_amdgcn_mfma_f32_16x16x32_bf16(a1, bfr[1][1], acc1, 0, 0, 0);
        #pragma unroll
        for (int ri = 0; ri < 4; ri++) {
            int pe = perm[base + kq * 4 + ri];
            float nn = 0.f;
            int d = 0;
            if (pe >= 0) { nn = norm[pe]; d = dst[pe]; }
            float* orow = out + d * 32;
            unsafeAtomicAdd(orow + 2 * c16,     acc0[ri] * nn);
            unsafeAtomicAdd(orow + 2 * c16 + 1, acc1[ri] * nn);
        }
    }
}

__global__ void bias2_kernel(float* __restrict__ out, const float* __restrict__ b) {
    const int total = N_NODES * OUT_DIM;
    for (int idx = blockIdx.x * blockDim.x + threadIdx.x; idx < total;
         idx += gridDim.x * blockDim.x)
        out[idx] += b[idx & (OUT_DIM - 1)];
}

extern "C" void kernel_launch(void* const* d_in, const int* in_sizes, int n_in,
                              void* d_out, int out_size, void* d_ws, size_t ws_size,
                              hipStream_t stream) {
    const int*   src   = (const int*)d_in[0];
    const int*   dst   = (const int*)d_in[1];
    const int*   etype = (const int*)d_in[2];
    const float* norm  = (const float*)d_in[3];
    const float* emb   = (const float*)d_in[4];
    const float* V1    = (const float*)d_in[5];
    const float* c1    = (const float*)d_in[6];
    const float* b1    = (const float*)d_in[7];
    const float* V2    = (const float*)d_in[8];
    const float* c2    = (const float*)d_in[9];
    const float* b2    = (const float*)d_in[10];
    float* out = (float*)d_out;
    char* ws = (char*)d_ws;

    // ---- Path A layout (identical extents to round 11; NEED_A = 251,241,088) ----
    unsigned short* W1s = (unsigned short*)(ws);                 // @0          524,288
    unsigned short* W2s = (unsigned short*)(ws + 524288);        //             262,144
    unsigned short* xb  = (unsigned short*)(ws + 786432);        //          12,800,000
    unsigned short* hbA = (unsigned short*)(ws + 13586432);      //          12,800,000
    int2*  ssP   = (int2*)(ws + 26386432);                       //          12,832,768
    float* normP = (float*)(ws + 39219200);                      //           6,420,480
    int*   noff  = (int*)(ws + 45639680);                        //             400,128
    int*   dcnt  = (int*)(ws + 46039808);                        //             400,000
    int* counts  = (int*)(ws + 46439808);                        //                 256
    int*   offs  = (int*)(ws + 46440064);                        //                 512
    int*  cur64  = (int*)(ws + 46440576);                        //                 512
    unsigned short* msg = (unsigned short*)(ws + 46441088);      //         204,800,000
    const size_t NEED_A = 46441088ull + 204800000ull;            //     251,241,088

    // rank aliases the head of msg (dead before edge1 writes msg)
    int* rank = (int*)msg;                       // 6,400,000 B
    // aliased into hbA (dead until segsum1): scan scratch + 8-way sub-counters
    int* nloc  = (int*)hbA;                                   // [0, 400,000)
    int* bsum  = (int*)(ws + 13586432 + 400128);              // 100 ints
    int* dcnt8 = (int*)(ws + 13586432 + 524288);              // [512K, 512K+3.2M) in hbA

    if (ws_size >= NEED_A) {
        // ================= PATH A: atomic-free, perm-ordered metadata =================
        (void)hipMemsetAsync(counts, 0, 256, stream);
        (void)hipMemsetAsync(dcnt8, 0, (size_t)N_NODES * 8 * 4, stream);

        build_w_swz<<<1536, 256, 0, stream>>>(V1, c1, V2, c2, W1s, W2s);
        cvt_bf16_kernel<<<6250, 256, 0, stream>>>(emb, xb, (N_NODES * H_DIM) / 4);
        hist_rank8<<<2048, 256, 0, stream>>>(etype, dst, counts, dcnt8, rank);
        scan_kernel<<<1, 64, 0, stream>>>(counts, offs, cur64, N_RELS);
        sub_scan<<<391, 256, 0, stream>>>(dcnt8, dcnt);
        scan_a<<<98, 1024, 0, stream>>>(dcnt, nloc, bsum);
        scan_b<<<1, 64, 0, stream>>>(bsum, 98);
        scan_c<<<98, 1024, 0, stream>>>(nloc, bsum, noff);
        scatter_big<<<782, 256, 0, stream>>>(etype, src, dst, norm, rank, noff,
                                             dcnt8, cur64, ssP, normP);
        edge1_mfmaA<<<2048, 256, 0, stream>>>(ssP, normP, xb, W1s, msg, offs, counts);
        segsum1<<<25000, 256, 0, stream>>>(msg, noff, b1, hbA);
        edge2_mfmaA<<<2048, 256, 0, stream>>>(ssP, normP, hbA, W2s, msg, offs, counts);
        segsum2<<<12500, 256, 0, stream>>>(msg, noff, b2, out);
    } else {
        // ================= PATH B: fallback =================
        unsigned short* hbB = xb;                                // alias
        float* h    = (float*)(ws + 13586432);                   // 25,600,000
        int*   permB = (int*)(ws + 39186432);                    //  6,416,384
        int* countsB = (int*)(ws + 45602816);
        int*   offsB = (int*)(ws + 45603072);
        int* cursorB = (int*)(ws + 45603584);

        (void)hipMemsetAsync(h, 0, (size_t)N_NODES * H_DIM * 4, stream);
        (void)hipMemsetAsync(out, 0, (size_t)out_size * 4, stream);
        (void)hipMemsetAsync(countsB, 0, 256, stream);
        (void)hipMemsetAsync(permB, 0xFF, (size_t)(N_EDGES + 4096) * 4, stream);

        build_w_swz<<<1536, 256, 0, stream>>>(V1, c1, V2, c2, W1s, W2s);
        cvt_bf16_kernel<<<6250, 256, 0, stream>>>(emb, xb, (N_NODES * H_DIM) / 4);
        hist_kernel<<<1024, 256, 0, stream>>>(etype, countsB);
        scan_kernel<<<1, 64, 0, stream>>>(countsB, offsB, cursorB, N_RELS);
        scatter_kernel<<<2048, 256, 0, stream>>>(etype, cursorB, permB);
        edge1_mfmaB<<<2048, 256, 0, stream>>>(permB, src, dst, norm, xb, W1s, h, offsB);
        bias_relu_bf<<<6250, 256, 0, stream>>>(h, b1, hbB, (N_NODES * H_DIM) / 4);
        edge2_mfmaB<<<2048, 256, 0, stream>>>(permB, src, dst, norm, hbB, W2s, out, offsB);
        bias2_kernel<<<4096, 256, 0, stream>>>(out, b2);
    }
}

// Round 13
// 356.950 us; speedup vs baseline: 1.1104x; 1.1104x over previous
//
#include <hip/hip_runtime.h>
#include <hip/hip_bf16.h>

#define N_NODES 100000
#define H_DIM 64
#define OUT_DIM 32
#define N_RELS 64
#define N_BASES 16
#define N_EDGES 1600000

typedef __attribute__((ext_vector_type(8))) short short8;
typedef __attribute__((ext_vector_type(4))) float f32x4;

__device__ __forceinline__ unsigned short f2bf(float f) {
    unsigned int u = __float_as_uint(f);
    u = (u + 0x7FFFu + ((u >> 16) & 1u)) >> 16;
    return (unsigned short)u;
}
__device__ __forceinline__ float bf2f(unsigned short u) {
    return __uint_as_float(((unsigned int)u) << 16);
}
__device__ __forceinline__ float shfl_f(float v, int l) {
    return __shfl(v, l, 64);
}
__device__ __forceinline__ int shfl_i(int v, int l) {
    return __shfl(v, l, 64);
}

// =========================================================================
// FUSED PREP: one kernel, three block roles (overlap latency-bound hist
// atomics with BW-bound cvt and VALU-bound build_w — same-stream kernels
// serialize, so single-kernel fusion is the only overlap mechanism).
//   blocks [0,1536):        build W1s/W2s (bf16, MFMA-B-fragment swizzled)
//   blocks [1536,2560):     etype hist + dst hist + local dst-rank (atomics)
//   blocks [2560,4160):     emb fp32 -> bf16
// =========================================================================
#define PREP_BW  1536
#define PREP_HIST 1024
#define PREP_CVT 1600

__global__ void __launch_bounds__(256) prep_fused(
    const float* __restrict__ V1, const float* __restrict__ c1,
    const float* __restrict__ V2, const float* __restrict__ c2,
    unsigned short* __restrict__ W1s, unsigned short* __restrict__ W2s,
    const float* __restrict__ emb, unsigned short* __restrict__ xb,
    const int* __restrict__ etype, const int* __restrict__ dst,
    int* __restrict__ counts, int* __restrict__ dcnt, int* __restrict__ rank) {
    __shared__ int lbin[N_RELS];
    const int b = blockIdx.x;
    if (b < PREP_BW) {
        // ---- build_w role (grid exactly covers n1+n2 = 393216 = 1536*256) ----
        int idx = b * 256 + threadIdx.x;
        const int n1 = N_RELS * 4096;
        if (idx < n1) {
            int r = idx >> 12;
            int f = idx & 4095;
            int nb = f >> 10, kb = (f >> 9) & 1, s = f & 511;
            int lane = s >> 3, j = s & 7;
            int k = 32 * kb + 8 * (lane >> 4) + j;
            int col = ((nb >> 1) << 5) + 2 * (lane & 15) + (nb & 1);
            float acc = 0.f;
            #pragma unroll
            for (int bb = 0; bb < N_BASES; bb++)
                acc += c1[r * N_BASES + bb] * V1[(bb * 64 + k) * 64 + col];
            W1s[idx] = f2bf(acc);
        } else {
            int t = idx - n1;
            int r = t >> 11;
            int f = t & 2047;
            int nb = f >> 10, kb = (f >> 9) & 1, s = f & 511;
            int lane = s >> 3, j = s & 7;
            int k = 32 * kb + 8 * (lane >> 4) + j;
            int col = 2 * (lane & 15) + nb;
            float acc = 0.f;
            #pragma unroll
            for (int bb = 0; bb < N_BASES; bb++)
                acc += c2[r * N_BASES + bb] * V2[(bb * 64 + k) * 32 + col];
            W2s[t] = f2bf(acc);
        }
    } else if (b < PREP_BW + PREP_HIST) {
        // ---- hist + rank role (r11-proven placement of the dcur atomic) ----
        const int bb = b - PREP_BW;
        for (int i = threadIdx.x; i < N_RELS; i += 256) lbin[i] = 0;
        __syncthreads();
        for (int e = bb * 256 + threadIdx.x; e < N_EDGES; e += PREP_HIST * 256) {
            atomicAdd(&lbin[etype[e]], 1);
            rank[e] = atomicAdd(&dcnt[dst[e]], 1);   // local rank within dst bin
        }
        __syncthreads();
        for (int i = threadIdx.x; i < N_RELS; i += 256)
            if (lbin[i]) atomicAdd(&counts[i], lbin[i]);
    } else {
        // ---- cvt role: emb (fp32) -> xb (bf16), grid-stride over float4s ----
        const int bb = b - PREP_BW - PREP_HIST;
        const int n4 = (N_NODES * H_DIM) / 4;
        for (int i = bb * 256 + threadIdx.x; i < n4; i += PREP_CVT * 256) {
            float4 v = ((const float4*)emb)[i];
            ushort4 o;
            o.x = f2bf(v.x); o.y = f2bf(v.y); o.z = f2bf(v.z); o.w = f2bf(v.w);
            ((ushort4*)xb)[i] = o;
        }
    }
}

// ---------- plain etype histogram (Path B) ----------
__global__ void hist_kernel(const int* __restrict__ etype, int* __restrict__ counts) {
    __shared__ int lbin[N_RELS];
    for (int i = threadIdx.x; i < N_RELS; i += blockDim.x) lbin[i] = 0;
    __syncthreads();
    for (int e = blockIdx.x * blockDim.x + threadIdx.x; e < N_EDGES;
         e += gridDim.x * blockDim.x)
        atomicAdd(&lbin[etype[e]], 1);
    __syncthreads();
    for (int i = threadIdx.x; i < N_RELS; i += blockDim.x)
        if (lbin[i]) atomicAdd(&counts[i], lbin[i]);
}

// ---------- fp32 -> bf16 (Path B) ----------
__global__ void cvt_bf16_kernel(const float* __restrict__ in,
                                unsigned short* __restrict__ outp, int n4) {
    int i = blockIdx.x * blockDim.x + threadIdx.x;
    if (i < n4) {
        float4 v = ((const float4*)in)[i];
        ushort4 o;
        o.x = f2bf(v.x); o.y = f2bf(v.y); o.z = f2bf(v.z); o.w = f2bf(v.w);
        ((ushort4*)outp)[i] = o;
    }
}

// ---------- build_w (Path B) ----------
__global__ void build_w_swz(const float* __restrict__ V1, const float* __restrict__ c1,
                            const float* __restrict__ V2, const float* __restrict__ c2,
                            unsigned short* __restrict__ W1s, unsigned short* __restrict__ W2s) {
    int idx = blockIdx.x * blockDim.x + threadIdx.x;
    const int n1 = N_RELS * 4096;
    const int n2 = N_RELS * 2048;
    if (idx < n1) {
        int r = idx >> 12;
        int f = idx & 4095;
        int nb = f >> 10, kb = (f >> 9) & 1, s = f & 511;
        int lane = s >> 3, j = s & 7;
        int k = 32 * kb + 8 * (lane >> 4) + j;
        int col = ((nb >> 1) << 5) + 2 * (lane & 15) + (nb & 1);
        float acc = 0.f;
        #pragma unroll
        for (int b = 0; b < N_BASES; b++)
            acc += c1[r * N_BASES + b] * V1[(b * 64 + k) * 64 + col];
        W1s[idx] = f2bf(acc);
    } else if (idx < n1 + n2) {
        int t = idx - n1;
        int r = t >> 11;
        int f = t & 2047;
        int nb = f >> 10, kb = (f >> 9) & 1, s = f & 511;
        int lane = s >> 3, j = s & 7;
        int k = 32 * kb + 8 * (lane >> 4) + j;
        int col = 2 * (lane & 15) + nb;
        float acc = 0.f;
        #pragma unroll
        for (int b = 0; b < N_BASES; b++)
            acc += c2[r * N_BASES + b] * V2[(b * 64 + k) * 32 + col];
        W2s[t] = f2bf(acc);
    }
}

// ---------- exclusive scan (nbins) with 64-alignment padding ----------
__global__ void scan_kernel(const int* __restrict__ counts, int* __restrict__ offs,
                            int* __restrict__ cursor, int nbins) {
    if (threadIdx.x == 0 && blockIdx.x == 0) {
        int L = 0;
        for (int r = 0; r < nbins; r++) {
            offs[r] = L;
            cursor[r] = L;
            L += (counts[r] + 63) & ~63;
        }
        offs[nbins] = L;
    }
}

// ---------- hierarchical scan over 100K dst bins ----------
__global__ void __launch_bounds__(1024) scan_a(const int* __restrict__ dcnt,
                                               int* __restrict__ nloc,
                                               int* __restrict__ bsum) {
    __shared__ int ps[1024];
    int t = threadIdx.x;
    int i = blockIdx.x * 1024 + t;
    int v = (i < N_NODES) ? dcnt[i] : 0;
    ps[t] = v;
    __syncthreads();
    int x = v;
    for (int off = 1; off < 1024; off <<= 1) {
        int y = (t >= off) ? ps[t - off] : 0;
        __syncthreads();
        x += y;
        ps[t] = x;
        __syncthreads();
    }
    if (i < N_NODES) nloc[i] = x - v;
    if (t == 1023) bsum[blockIdx.x] = x;
}

__global__ void scan_b(int* __restrict__ bsum, int nb) {
    if (threadIdx.x == 0 && blockIdx.x == 0) {
        int s = 0;
        for (int i = 0; i < nb; i++) { int t = bsum[i]; bsum[i] = s; s += t; }
        bsum[nb] = s;
    }
}

__global__ void __launch_bounds__(1024) scan_c(const int* __restrict__ nloc,
                                               const int* __restrict__ bsum,
                                               int* __restrict__ noff) {
    int t = threadIdx.x;
    int i = blockIdx.x * 1024 + t;
    if (i < N_NODES) noff[i] = nloc[i] + bsum[blockIdx.x];
    if (i == 0) noff[N_NODES] = bsum[(N_NODES + 1023) / 1024];
}

// ---------- 64-bucket scatter: perm-ordered metadata, NO atomic returns ----------
__global__ void __launch_bounds__(256) scatter_big(
    const int* __restrict__ etype, const int* __restrict__ src,
    const int* __restrict__ dst, const float* __restrict__ norm,
    const int* __restrict__ rank, const int* __restrict__ noff,
    int* __restrict__ cursor, int2* __restrict__ ssP, float* __restrict__ normP) {
    __shared__ int lbin[N_RELS];
    __shared__ int lbase[N_RELS];
    const int base = blockIdx.x * 2048;
    for (int i = threadIdx.x; i < N_RELS; i += 256) lbin[i] = 0;
    __syncthreads();
    int rr[8], lp[8];
    #pragma unroll
    for (int k = 0; k < 8; k++) {
        int e = base + k * 256 + threadIdx.x;
        rr[k] = -1;
        if (e < N_EDGES) {
            rr[k] = etype[e];
            lp[k] = atomicAdd(&lbin[rr[k]], 1);
        }
    }
    __syncthreads();
    for (int i = threadIdx.x; i < N_RELS; i += 256)
        lbase[i] = lbin[i] ? atomicAdd(&cursor[i], lbin[i]) : 0;
    __syncthreads();
    #pragma unroll
    for (int k = 0; k < 8; k++) {
        int e = base + k * 256 + threadIdx.x;
        if (rr[k] >= 0) {
            int pos = lbase[rr[k]] + lp[k];
            int slot = rank[e] + noff[dst[e]];
            ssP[pos] = make_int2(src[e], slot);
            normP[pos] = norm[e];
        }
    }
}

// ---------- plain rel-bucket scatter (Path B) ----------
__global__ void scatter_kernel(const int* __restrict__ etype, int* __restrict__ cursor,
                               int* __restrict__ perm) {
    __shared__ int lbin[N_RELS];
    __shared__ int lbase[N_RELS];
    const int nChunks = (N_EDGES + 255) >> 8;
    for (int chunk = blockIdx.x; chunk < nChunks; chunk += gridDim.x) {
        for (int i = threadIdx.x; i < N_RELS; i += blockDim.x) lbin[i] = 0;
        __syncthreads();
        int e = chunk * 256 + threadIdx.x;
        int r = -1, lpos = 0;
        if (e < N_EDGES) {
            r = etype[e];
            lpos = atomicAdd(&lbin[r], 1);
        }
        __syncthreads();
        for (int i = threadIdx.x; i < N_RELS; i += blockDim.x)
            lbase[i] = lbin[i] ? atomicAdd(&cursor[i], lbin[i]) : 0;
        __syncthreads();
        if (e < N_EDGES) perm[lbase[r] + lpos] = e;
        __syncthreads();
    }
}

// =========================================================================
// PATH A edge kernels: 2-stage pipeline; index phase = 2 COALESCED loads
// (int2 ssP + float normP in perm order) + 1 random 128B gather.
// =========================================================================
__global__ void __launch_bounds__(256) edge1_mfmaA(
    const int2* __restrict__ ssP, const float* __restrict__ normP,
    const unsigned short* __restrict__ xb, const unsigned short* __restrict__ Ws,
    unsigned short* __restrict__ msg, const int* __restrict__ offs,
    const int* __restrict__ cnts) {
    const int lane = threadIdx.x & 63;
    const int wave = (blockIdx.x * blockDim.x + threadIdx.x) >> 6;
    const int nw = (gridDim.x * blockDim.x) >> 6;
    const int wpb = nw >> 6;
    const int r = wave / wpb;
    const int sub = wave - r * wpb;
    const int b0 = offs[r];
    const int cnt = cnts[r];
    const int ntiles = (cnt + 15) >> 4;
    const int c16 = lane & 15, kq = lane >> 4;

    const unsigned short* Wr = Ws + r * 4096 + lane * 8;
    short8 bfr[4][2];
    #pragma unroll
    for (int nb = 0; nb < 4; nb++)
        #pragma unroll
        for (int kb = 0; kb < 2; kb++)
            bfr[nb][kb] = *(const short8*)(Wr + ((nb * 2 + kb) << 9));

    int t = sub;
    if (t >= ntiles) return;

    float nnC; int slC; short8 a0, a1;
    {
        const int base = b0 + (t << 4);
        const int rem = cnt - (t << 4);
        int2 ss = ssP[base + c16];
        nnC = normP[base + c16];
        slC = ss.y;
        int sa = (c16 < rem) ? ss.x : 0;
        const unsigned short* xr = xb + sa * 64 + kq * 8;
        a0 = *(const short8*)(xr);
        a1 = *(const short8*)(xr + 32);
    }

    while (t < ntiles) {
        const int tn = t + wpb;
        float nnN = 0.f; int slN = 0; short8 a0N = a0, a1N = a1;
        if (tn < ntiles) {
            const int baseN = b0 + (tn << 4);
            const int remN = cnt - (tn << 4);
            int2 ssN = ssP[baseN + c16];
            nnN = normP[baseN + c16];
            slN = ssN.y;
            int saN = (c16 < remN) ? ssN.x : 0;
            const unsigned short* xrN = xb + saN * 64 + kq * 8;
            a0N = *(const short8*)(xrN);
            a1N = *(const short8*)(xrN + 32);
        }
        const int rem = cnt - (t << 4);
        f32x4 acc0{0.f, 0.f, 0.f, 0.f}, acc1{0.f, 0.f, 0.f, 0.f};
        f32x4 acc2{0.f, 0.f, 0.f, 0.f}, acc3{0.f, 0.f, 0.f, 0.f};
        acc0 = __builtin_amdgcn_mfma_f32_16x16x32_bf16(a0, bfr[0][0], acc0, 0, 0, 0);
        acc0 = __builtin_amdgcn_mfma_f32_16x16x32_bf16(a1, bfr[0][1], acc0, 0, 0, 0);
        acc1 = __builtin_amdgcn_mfma_f32_16x16x32_bf16(a0, bfr[1][0], acc1, 0, 0, 0);
        acc1 = __builtin_amdgcn_mfma_f32_16x16x32_bf16(a1, bfr[1][1], acc1, 0, 0, 0);
        acc2 = __builtin_amdgcn_mfma_f32_16x16x32_bf16(a0, bfr[2][0], acc2, 0, 0, 0);
        acc2 = __builtin_amdgcn_mfma_f32_16x16x32_bf16(a1, bfr[2][1], acc2, 0, 0, 0);
        acc3 = __builtin_amdgcn_mfma_f32_16x16x32_bf16(a0, bfr[3][0], acc3, 0, 0, 0);
        acc3 = __builtin_amdgcn_mfma_f32_16x16x32_bf16(a1, bfr[3][1], acc3, 0, 0, 0);
        #pragma unroll
        for (int ri = 0; ri < 4; ri++) {
            int li = kq * 4 + ri;
            bool valid = li < rem;
            float nn = shfl_f(nnC, li);
            int slot = shfl_i(slC, li);
            if (valid) {
                unsigned int p01 = (unsigned int)f2bf(acc0[ri] * nn) |
                                   ((unsigned int)f2bf(acc1[ri] * nn) << 16);
                unsigned int p23 = (unsigned int)f2bf(acc2[ri] * nn) |
                                   ((unsigned int)f2bf(acc3[ri] * nn) << 16);
                unsigned int* mp = (unsigned int*)(msg + (size_t)slot * 64);
                __builtin_nontemporal_store(p01, mp + c16);
                __builtin_nontemporal_store(p23, mp + 16 + c16);
            }
        }
        nnC = nnN; slC = slN; a0 = a0N; a1 = a1N;
        t = tn;
    }
}

__global__ void __launch_bounds__(256) edge2_mfmaA(
    const int2* __restrict__ ssP, const float* __restrict__ normP,
    const unsigned short* __restrict__ hb, const unsigned short* __restrict__ Ws,
    unsigned short* __restrict__ msg, const int* __restrict__ offs,
    const int* __restrict__ cnts) {
    const int lane = threadIdx.x & 63;
    const int wave = (blockIdx.x * blockDim.x + threadIdx.x) >> 6;
    const int nw = (gridDim.x * blockDim.x) >> 6;
    const int wpb = nw >> 6;
    const int r = wave / wpb;
    const int sub = wave - r * wpb;
    const int b0 = offs[r];
    const int cnt = cnts[r];
    const int ntiles = (cnt + 15) >> 4;
    const int c16 = lane & 15, kq = lane >> 4;

    const unsigned short* Wr = Ws + r * 2048 + lane * 8;
    short8 bfr[2][2];
    #pragma unroll
    for (int nb = 0; nb < 2; nb++)
        #pragma unroll
        for (int kb = 0; kb < 2; kb++)
            bfr[nb][kb] = *(const short8*)(Wr + ((nb * 2 + kb) << 9));

    int t = sub;
    if (t >= ntiles) return;

    float nnC; int slC; short8 a0, a1;
    {
        const int base = b0 + (t << 4);
        const int rem = cnt - (t << 4);
        int2 ss = ssP[base + c16];
        nnC = normP[base + c16];
        slC = ss.y;
        int sa = (c16 < rem) ? ss.x : 0;
        const unsigned short* xr = hb + sa * 64 + kq * 8;
        a0 = *(const short8*)(xr);
        a1 = *(const short8*)(xr + 32);
    }

    while (t < ntiles) {
        const int tn = t + wpb;
        float nnN = 0.f; int slN = 0; short8 a0N = a0, a1N = a1;
        if (tn < ntiles) {
            const int baseN = b0 + (tn << 4);
            const int remN = cnt - (tn << 4);
            int2 ssN = ssP[baseN + c16];
            nnN = normP[baseN + c16];
            slN = ssN.y;
            int saN = (c16 < remN) ? ssN.x : 0;
            const unsigned short* xrN = hb + saN * 64 + kq * 8;
            a0N = *(const short8*)(xrN);
            a1N = *(const short8*)(xrN + 32);
        }
        const int rem = cnt - (t << 4);
        f32x4 acc0{0.f, 0.f, 0.f, 0.f}, acc1{0.f, 0.f, 0.f, 0.f};
        acc0 = __builtin_amdgcn_mfma_f32_16x16x32_bf16(a0, bfr[0][0], acc0, 0, 0, 0);
        acc0 = __builtin_amdgcn_mfma_f32_16x16x32_bf16(a1, bfr[0][1], acc0, 0, 0, 0);
        acc1 = __builtin_amdgcn_mfma_f32_16x16x32_bf16(a0, bfr[1][0], acc1, 0, 0, 0);
        acc1 = __builtin_amdgcn_mfma_f32_16x16x32_bf16(a1, bfr[1][1], acc1, 0, 0, 0);
        #pragma unroll
        for (int ri = 0; ri < 4; ri++) {
            int li = kq * 4 + ri;
            bool valid = li < rem;
            float nn = shfl_f(nnC, li);
            int slot = shfl_i(slC, li);
            if (valid) {
                unsigned int p01 = (unsigned int)f2bf(acc0[ri] * nn) |
                                   ((unsigned int)f2bf(acc1[ri] * nn) << 16);
                __builtin_nontemporal_store(p01,
                    (unsigned int*)(msg + (size_t)slot * 32) + c16);
            }
        }
        nnC = nnN; slC = slN; a0 = a0N; a1 = a1N;
        t = tn;
    }
}

// ---------- segment sums (nontemporal msg reads, 4-deep ILP) ----------
__global__ void __launch_bounds__(256) segsum1(const unsigned short* __restrict__ msg,
                                               const int* __restrict__ noff,
                                               const float* __restrict__ b1,
                                               unsigned short* __restrict__ hb) {
    int v = (blockIdx.x * blockDim.x + threadIdx.x) >> 6;
    int lane = threadIdx.x & 63;
    if (v >= N_NODES) return;
    int s0 = noff[v], s1 = noff[v + 1];
    float a0 = 0.f, a1 = 0.f, a2 = 0.f, a3 = 0.f;
    int i = s0;
    for (; i + 3 < s1; i += 4) {
        a0 += bf2f(__builtin_nontemporal_load(msg + (size_t)i * 64 + lane));
        a1 += bf2f(__builtin_nontemporal_load(msg + (size_t)(i + 1) * 64 + lane));
        a2 += bf2f(__builtin_nontemporal_load(msg + (size_t)(i + 2) * 64 + lane));
        a3 += bf2f(__builtin_nontemporal_load(msg + (size_t)(i + 3) * 64 + lane));
    }
    for (; i < s1; i++)
        a0 += bf2f(__builtin_nontemporal_load(msg + (size_t)i * 64 + lane));
    float val = fmaxf((a0 + a1) + (a2 + a3) + b1[lane], 0.f);
    hb[v * 64 + lane] = f2bf(val);
}

__global__ void __launch_bounds__(256) segsum2(const unsigned short* __restrict__ msg,
                                               const int* __restrict__ noff,
                                               const float* __restrict__ b2,
                                               float* __restrict__ out) {
    int idx = blockIdx.x * blockDim.x + threadIdx.x;
    int v = idx >> 5, o = idx & 31;
    if (v >= N_NODES) return;
    int s0 = noff[v], s1 = noff[v + 1];
    float a0 = 0.f, a1 = 0.f, a2 = 0.f, a3 = 0.f;
    int i = s0;
    for (; i + 3 < s1; i += 4) {
        a0 += bf2f(__builtin_nontemporal_load(msg + (size_t)i * 32 + o));
        a1 += bf2f(__builtin_nontemporal_load(msg + (size_t)(i + 1) * 32 + o));
        a2 += bf2f(__builtin_nontemporal_load(msg + (size_t)(i + 2) * 32 + o));
        a3 += bf2f(__builtin_nontemporal_load(msg + (size_t)(i + 3) * 32 + o));
    }
    for (; i < s1; i++)
        a0 += bf2f(__builtin_nontemporal_load(msg + (size_t)i * 32 + o));
    out[v * 32 + o] = (a0 + a1) + (a2 + a3) + b2[o];
}

// =========================================================================
// PATH B: atomics fallback — used only if ws_size is too small.
// =========================================================================
__global__ void __launch_bounds__(256) edge1_mfmaB(
    const int* __restrict__ perm, const int* __restrict__ src,
    const int* __restrict__ dst, const float* __restrict__ norm,
    const unsigned short* __restrict__ xb, const unsigned short* __restrict__ Ws,
    float* __restrict__ hout, const int* __restrict__ offs) {
    const int lane = threadIdx.x & 63;
    const int wave = (blockIdx.x * blockDim.x + threadIdx.x) >> 6;
    const int nw = (gridDim.x * blockDim.x) >> 6;
    const int wpb = nw >> 6;
    const int r = wave / wpb;
    const int sub = wave - r * wpb;
    const int b0 = offs[r], b1v = offs[r + 1];
    const int ntiles = (b1v - b0) >> 4;
    const int c16 = lane & 15, kq = lane >> 4;
    const unsigned short* Wr = Ws + r * 4096 + lane * 8;
    short8 bfr[4][2];
    #pragma unroll
    for (int nb = 0; nb < 4; nb++)
        #pragma unroll
        for (int kb = 0; kb < 2; kb++)
            bfr[nb][kb] = *(const short8*)(Wr + ((nb * 2 + kb) << 9));
    for (int t = sub; t < ntiles; t += wpb) {
        const int base = b0 + (t << 4);
        int pa = perm[base + c16];
        int sa = pa < 0 ? 0 : src[pa];
        const unsigned short* xr = xb + sa * 64 + kq * 8;
        short8 a0 = *(const short8*)(xr);
        short8 a1 = *(const short8*)(xr + 32);
        f32x4 acc0{0.f, 0.f, 0.f, 0.f}, acc1{0.f, 0.f, 0.f, 0.f};
        f32x4 acc2{0.f, 0.f, 0.f, 0.f}, acc3{0.f, 0.f, 0.f, 0.f};
        acc0 = __builtin_amdgcn_mfma_f32_16x16x32_bf16(a0, bfr[0][0], acc0, 0, 0, 0);
        acc0 = __builtin_amdgcn_mfma_f32_16x16x32_bf16(a1, bfr[0][1], acc0, 0, 0, 0);
        acc1 = __builtin_amdgcn_mfma_f32_16x16x32_bf16(a0, bfr[1][0], acc1, 0, 0, 0);
        acc1 = __builtin_amdgcn_mfma_f32_16x16x32_bf16(a1, bfr[1][1], acc1, 0, 0, 0);
        acc2 = __builtin_amdgcn_mfma_f32_16x16x32_bf16(a0, bfr[2][0], acc2, 0, 0, 0);
        acc2 = __builtin_amdgcn_mfma_f32_16x16x32_bf16(a1, bfr[2][1], acc2, 0, 0, 0);
        acc3 = __builtin_amdgcn_mfma_f32_16x16x32_bf16(a0, bfr[3][0], acc3, 0, 0, 0);
        acc3 = __builtin_amdgcn_mfma_f32_16x16x32_bf16(a1, bfr[3][1], acc3, 0, 0, 0);
        #pragma unroll
        for (int ri = 0; ri < 4; ri++) {
            int pe = perm[base + kq * 4 + ri];
            float nn = 0.f;
            int d = 0;
            if (pe >= 0) { nn = norm[pe]; d = dst[pe]; }
            float* hrow = hout + d * 64;
            unsafeAtomicAdd(hrow + 2 * c16,      acc0[ri] * nn);
            unsafeAtomicAdd(hrow + 2 * c16 + 1,  acc1[ri] * nn);
            unsafeAtomicAdd(hrow + 32 + 2 * c16, acc2[ri] * nn);
            unsafeAtomicAdd(hrow + 33 + 2 * c16, acc3[ri] * nn);
        }
    }
}

__global__ void bias_relu_bf(const float* __restrict__ h, const float* __restrict__ b,
                             unsigned short* __restrict__ hb, int n4) {
    int i = blockIdx.x * blockDim.x + threadIdx.x;
    if (i < n4) {
        float4 v = ((const float4*)h)[i];
        float4 bv = ((const float4*)b)[i & 15];
        ushort4 o;
        o.x = f2bf(fmaxf(v.x + bv.x, 0.f));
        o.y = f2bf(fmaxf(v.y + bv.y, 0.f));
        o.z = f2bf(fmaxf(v.z + bv.z, 0.f));
        o.w = f2bf(fmaxf(v.w + bv.w, 0.f));
        ((ushort4*)hb)[i] = o;
    }
}

__global__ void __launch_bounds__(256) edge2_mfmaB(
    const int* __restrict__ perm, const int* __restrict__ src,
    const int* __restrict__ dst, const float* __restrict__ norm,
    const unsigned short* __restrict__ hb, const unsigned short* __restrict__ Ws,
    float* __restrict__ out, const int* __restrict__ offs) {
    const int lane = threadIdx.x & 63;
    const int wave = (blockIdx.x * blockDim.x + threadIdx.x) >> 6;
    const int nw = (gridDim.x * blockDim.x) >> 6;
    const int wpb = nw >> 6;
    const int r = wave / wpb;
    const int sub = wave - r * wpb;
    const int b0 = offs[r], b1v = offs[r + 1];
    const int ntiles = (b1v - b0) >> 4;
    const int c16 = lane & 15, kq = lane >> 4;
    const unsigned short* Wr = Ws + r * 2048 + lane * 8;
    short8 bfr[2][2];
    #pragma unroll
    for (int nb = 0; nb < 2; nb++)
        #pragma unroll
        for (int kb = 0; kb < 2; kb++)
            bfr[nb][kb] = *(const short8*)(Wr + ((nb * 2 + kb) << 9));
    for (int t = sub; t < ntiles; t += wpb) {
        const int base = b0 + (t << 4);
        int pa = perm[base + c16];
        int sa = pa < 0 ? 0 : src[pa];
        const unsigned short* xr = hb + sa * 64 + kq * 8;
        short8 a0 = *(const short8*)(xr);
        short8 a1 = *(const short8*)(xr + 32);
        f32x4 acc0{0.f, 0.f, 0.f, 0.f}, acc1{0.f, 0.f, 0.f, 0.f};
        acc0 = __builtin_amdgcn_mfma_f32_16x16x32_bf16(a0, bfr[0][0], acc0, 0, 0, 0);
        acc0 = __builtin_amdgcn_mfma_f32_16x16x32_bf16(a1, bfr[0][1], acc0, 0, 0, 0);
        acc1 = __builtin_amdgcn_mfma_f32_16x16x32_bf16(a0, bfr[1][0], acc1, 0, 0, 0);
        acc1 = __builtin_amdgcn_mfma_f32_16x16x32_bf16(a1, bfr[1][1], acc1, 0, 0, 0);
        #pragma unroll
        for (int ri = 0; ri < 4; ri++) {
            int pe = perm[base + kq * 4 + ri];
            float nn = 0.f;
            int d = 0;
            if (pe >= 0) { nn = norm[pe]; d = dst[pe]; }
            float* orow = out + d * 32;
            unsafeAtomicAdd(orow + 2 * c16,     acc0[ri] * nn);
            unsafeAtomicAdd(orow + 2 * c16 + 1, acc1[ri] * nn);
        }
    }
}

__global__ void bias2_kernel(float* __restrict__ out, const float* __restrict__ b) {
    const int total = N_NODES * OUT_DIM;
    for (int idx = blockIdx.x * blockDim.x + threadIdx.x; idx < total;
         idx += gridDim.x * blockDim.x)
        out[idx] += b[idx & (OUT_DIM - 1)];
}

extern "C" void kernel_launch(void* const* d_in, const int* in_sizes, int n_in,
                              void* d_out, int out_size, void* d_ws, size_t ws_size,
                              hipStream_t stream) {
    const int*   src   = (const int*)d_in[0];
    const int*   dst   = (const int*)d_in[1];
    const int*   etype = (const int*)d_in[2];
    const float* norm  = (const float*)d_in[3];
    const float* emb   = (const float*)d_in[4];
    const float* V1    = (const float*)d_in[5];
    const float* c1    = (const float*)d_in[6];
    const float* b1    = (const float*)d_in[7];
    const float* V2    = (const float*)d_in[8];
    const float* c2    = (const float*)d_in[9];
    const float* b2    = (const float*)d_in[10];
    float* out = (float*)d_out;
    char* ws = (char*)d_ws;

    // ---- Path A layout (identical to round 11; NEED_A = 251,241,088) ----
    unsigned short* W1s = (unsigned short*)(ws);                 // @0          524,288
    unsigned short* W2s = (unsigned short*)(ws + 524288);        //             262,144
    unsigned short* xb  = (unsigned short*)(ws + 786432);        //          12,800,000
    unsigned short* hbA = (unsigned short*)(ws + 13586432);      //          12,800,000
    int2*  ssP   = (int2*)(ws + 26386432);                       //          12,832,768
    float* normP = (float*)(ws + 39219200);                      //           6,420,480
    int*   noff  = (int*)(ws + 45639680);                        //             400,128
    int*   dcnt  = (int*)(ws + 46039808);                        //             400,000
    int* counts  = (int*)(ws + 46439808);                        //                 256
    int*   offs  = (int*)(ws + 46440064);                        //                 512
    int*  cur64  = (int*)(ws + 46440576);                        //                 512
    unsigned short* msg = (unsigned short*)(ws + 46441088);      //         204,800,000
    const size_t NEED_A = 46441088ull + 204800000ull;            //     251,241,088

    // rank aliases the head of msg (dead before edge1 writes msg)
    int* rank = (int*)msg;                       // 6,400,000 B
    // scan scratch aliased into hbA (dead until segsum1)
    int* nloc = (int*)hbA;                       // 400,000 B
    int* bsum = (int*)(ws + 13586432 + 400128);  // 100 ints

    if (ws_size >= NEED_A) {
        // ================= PATH A: fused prep + atomic-free aggregation =================
        (void)hipMemsetAsync(counts, 0, 256, stream);
        (void)hipMemsetAsync(dcnt, 0, 400000, stream);

        prep_fused<<<PREP_BW + PREP_HIST + PREP_CVT, 256, 0, stream>>>(
            V1, c1, V2, c2, W1s, W2s, emb, xb, etype, dst, counts, dcnt, rank);
        scan_kernel<<<1, 64, 0, stream>>>(counts, offs, cur64, N_RELS);
        scan_a<<<98, 1024, 0, stream>>>(dcnt, nloc, bsum);
        scan_b<<<1, 64, 0, stream>>>(bsum, 98);
        scan_c<<<98, 1024, 0, stream>>>(nloc, bsum, noff);
        scatter_big<<<782, 256, 0, stream>>>(etype, src, dst, norm, rank, noff,
                                             cur64, ssP, normP);
        edge1_mfmaA<<<4096, 256, 0, stream>>>(ssP, normP, xb, W1s, msg, offs, counts);
        segsum1<<<25000, 256, 0, stream>>>(msg, noff, b1, hbA);
        edge2_mfmaA<<<4096, 256, 0, stream>>>(ssP, normP, hbA, W2s, msg, offs, counts);
        segsum2<<<12500, 256, 0, stream>>>(msg, noff, b2, out);
    } else {
        // ================= PATH B: fallback =================
        unsigned short* hbB = xb;                                // alias
        float* h    = (float*)(ws + 13586432);                   // 25,600,000
        int*   permB = (int*)(ws + 39186432);                    //  6,416,384
        int* countsB = (int*)(ws + 45602816);
        int*   offsB = (int*)(ws + 45603072);
        int* cursorB = (int*)(ws + 45603584);

        (void)hipMemsetAsync(h, 0, (size_t)N_NODES * H_DIM * 4, stream);
        (void)hipMemsetAsync(out, 0, (size_t)out_size * 4, stream);
        (void)hipMemsetAsync(countsB, 0, 256, stream);
        (void)hipMemsetAsync(permB, 0xFF, (size_t)(N_EDGES + 4096) * 4, stream);

        build_w_swz<<<1536, 256, 0, stream>>>(V1, c1, V2, c2, W1s, W2s);
        cvt_bf16_kernel<<<6250, 256, 0, stream>>>(emb, xb, (N_NODES * H_DIM) / 4);
        hist_kernel<<<1024, 256, 0, stream>>>(etype, countsB);
        scan_kernel<<<1, 64, 0, stream>>>(countsB, offsB, cursorB, N_RELS);
        scatter_kernel<<<2048, 256, 0, stream>>>(etype, cursorB, permB);
        edge1_mfmaB<<<2048, 256, 0, stream>>>(permB, src, dst, norm, xb, W1s, h, offsB);
        bias_relu_bf<<<6250, 256, 0, stream>>>(h, b1, hbB, (N_NODES * H_DIM) / 4);
        edge2_mfmaB<<<2048, 256, 0, stream>>>(permB, src, dst, norm, hbB, W2s, out, offsB);
        bias2_kernel<<<4096, 256, 0, stream>>>(out, b2);
    }
}

// Round 14
// 344.581 us; speedup vs baseline: 1.1502x; 1.0359x over previous
//
#include <hip/hip_runtime.h>
#include <hip/hip_bf16.h>

#define N_NODES 100000
#define H_DIM 64
#define OUT_DIM 32
#define N_RELS 64
#define N_BASES 16
#define N_EDGES 1600000

typedef __attribute__((ext_vector_type(8))) short short8;
typedef __attribute__((ext_vector_type(4))) float f32x4;

__device__ __forceinline__ unsigned short f2bf(float f) {
    unsigned int u = __float_as_uint(f);
    u = (u + 0x7FFFu + ((u >> 16) & 1u)) >> 16;
    return (unsigned short)u;
}
__device__ __forceinline__ float bf2f(unsigned short u) {
    return __uint_as_float(((unsigned int)u) << 16);
}
__device__ __forceinline__ float shfl_f(float v, int l) {
    return __shfl(v, l, 64);
}
__device__ __forceinline__ int shfl_i(int v, int l) {
    return __shfl(v, l, 64);
}

// =========================================================================
// FUSED PREP (r13-proven): three block roles overlap the latency-bound
// hist atomics with BW-bound cvt and VALU-bound build_w.
// =========================================================================
#define PREP_BW  1536
#define PREP_HIST 1024
#define PREP_CVT 1600

__global__ void __launch_bounds__(256) prep_fused(
    const float* __restrict__ V1, const float* __restrict__ c1,
    const float* __restrict__ V2, const float* __restrict__ c2,
    unsigned short* __restrict__ W1s, unsigned short* __restrict__ W2s,
    const float* __restrict__ emb, unsigned short* __restrict__ xb,
    const int* __restrict__ etype, const int* __restrict__ dst,
    int* __restrict__ counts, int* __restrict__ dcnt, int* __restrict__ rank) {
    __shared__ int lbin[N_RELS];
    const int b = blockIdx.x;
    if (b < PREP_BW) {
        int idx = b * 256 + threadIdx.x;
        const int n1 = N_RELS * 4096;
        if (idx < n1) {
            int r = idx >> 12;
            int f = idx & 4095;
            int nb = f >> 10, kb = (f >> 9) & 1, s = f & 511;
            int lane = s >> 3, j = s & 7;
            int k = 32 * kb + 8 * (lane >> 4) + j;
            int col = ((nb >> 1) << 5) + 2 * (lane & 15) + (nb & 1);
            float acc = 0.f;
            #pragma unroll
            for (int bb = 0; bb < N_BASES; bb++)
                acc += c1[r * N_BASES + bb] * V1[(bb * 64 + k) * 64 + col];
            W1s[idx] = f2bf(acc);
        } else {
            int t = idx - n1;
            int r = t >> 11;
            int f = t & 2047;
            int nb = f >> 10, kb = (f >> 9) & 1, s = f & 511;
            int lane = s >> 3, j = s & 7;
            int k = 32 * kb + 8 * (lane >> 4) + j;
            int col = 2 * (lane & 15) + nb;
            float acc = 0.f;
            #pragma unroll
            for (int bb = 0; bb < N_BASES; bb++)
                acc += c2[r * N_BASES + bb] * V2[(bb * 64 + k) * 32 + col];
            W2s[t] = f2bf(acc);
        }
    } else if (b < PREP_BW + PREP_HIST) {
        const int bb = b - PREP_BW;
        for (int i = threadIdx.x; i < N_RELS; i += 256) lbin[i] = 0;
        __syncthreads();
        for (int e = bb * 256 + threadIdx.x; e < N_EDGES; e += PREP_HIST * 256) {
            atomicAdd(&lbin[etype[e]], 1);
            rank[e] = atomicAdd(&dcnt[dst[e]], 1);   // local rank within dst bin
        }
        __syncthreads();
        for (int i = threadIdx.x; i < N_RELS; i += 256)
            if (lbin[i]) atomicAdd(&counts[i], lbin[i]);
    } else {
        const int bb = b - PREP_BW - PREP_HIST;
        const int n4 = (N_NODES * H_DIM) / 4;
        for (int i = bb * 256 + threadIdx.x; i < n4; i += PREP_CVT * 256) {
            float4 v = ((const float4*)emb)[i];
            ushort4 o;
            o.x = f2bf(v.x); o.y = f2bf(v.y); o.z = f2bf(v.z); o.w = f2bf(v.w);
            ((ushort4*)xb)[i] = o;
        }
    }
}

// ---------- merged scan stage 1: 98 blocks dst-scan + block 98 rel-scan ----------
__global__ void __launch_bounds__(1024) scan_a2(const int* __restrict__ dcnt,
                                                int* __restrict__ nloc,
                                                int* __restrict__ bsum,
                                                const int* __restrict__ counts,
                                                int* __restrict__ offs,
                                                int* __restrict__ cursor) {
    if (blockIdx.x == 98) {
        // rel-bucket exclusive scan (64 bins, 64-aligned padding)
        if (threadIdx.x == 0) {
            int L = 0;
            for (int r = 0; r < N_RELS; r++) {
                offs[r] = L;
                cursor[r] = L;
                L += (counts[r] + 63) & ~63;
            }
            offs[N_RELS] = L;
        }
        return;
    }
    __shared__ int ps[1024];
    int t = threadIdx.x;
    int i = blockIdx.x * 1024 + t;
    int v = (i < N_NODES) ? dcnt[i] : 0;
    ps[t] = v;
    __syncthreads();
    int x = v;
    for (int off = 1; off < 1024; off <<= 1) {
        int y = (t >= off) ? ps[t - off] : 0;
        __syncthreads();
        x += y;
        ps[t] = x;
        __syncthreads();
    }
    if (i < N_NODES) nloc[i] = x - v;
    if (t == 1023) bsum[blockIdx.x] = x;
}

// ---------- merged scan stage 2: inline serial prefix of the 98 bsums ----------
__global__ void __launch_bounds__(1024) scan_c2(const int* __restrict__ nloc,
                                                const int* __restrict__ bsum,
                                                int* __restrict__ noff) {
    __shared__ int base_s;
    int t = threadIdx.x;
    if (t == 0) {
        int s = 0;
        for (int b = 0; b < (int)blockIdx.x; b++) s += bsum[b];
        base_s = s;
        if (blockIdx.x == 0) {
            int tot = 0;
            for (int b = 0; b < 98; b++) tot += bsum[b];
            noff[N_NODES] = tot;
        }
    }
    __syncthreads();
    int i = blockIdx.x * 1024 + t;
    if (i < N_NODES) noff[i] = nloc[i] + base_s;
}

// ---------- 64-bucket scatter: perm-ordered metadata, NO atomic returns ----------
__global__ void __launch_bounds__(256) scatter_big(
    const int* __restrict__ etype, const int* __restrict__ src,
    const int* __restrict__ dst, const float* __restrict__ norm,
    const int* __restrict__ rank, const int* __restrict__ noff,
    int* __restrict__ cursor, int2* __restrict__ ssP, float* __restrict__ normP) {
    __shared__ int lbin[N_RELS];
    __shared__ int lbase[N_RELS];
    const int base = blockIdx.x * 2048;
    for (int i = threadIdx.x; i < N_RELS; i += 256) lbin[i] = 0;
    __syncthreads();
    int rr[8], lp[8];
    #pragma unroll
    for (int k = 0; k < 8; k++) {
        int e = base + k * 256 + threadIdx.x;
        rr[k] = -1;
        if (e < N_EDGES) {
            rr[k] = etype[e];
            lp[k] = atomicAdd(&lbin[rr[k]], 1);
        }
    }
    __syncthreads();
    for (int i = threadIdx.x; i < N_RELS; i += 256)
        lbase[i] = lbin[i] ? atomicAdd(&cursor[i], lbin[i]) : 0;
    __syncthreads();
    #pragma unroll
    for (int k = 0; k < 8; k++) {
        int e = base + k * 256 + threadIdx.x;
        if (rr[k] >= 0) {
            int pos = lbase[rr[k]] + lp[k];
            int slot = rank[e] + noff[dst[e]];
            ssP[pos] = make_int2(src[e], slot);
            normP[pos] = norm[e];
        }
    }
}

// =========================================================================
// PATH A edge kernels (r11-proven 2-stage pipeline)
// =========================================================================
__global__ void __launch_bounds__(256) edge1_mfmaA(
    const int2* __restrict__ ssP, const float* __restrict__ normP,
    const unsigned short* __restrict__ xb, const unsigned short* __restrict__ Ws,
    unsigned short* __restrict__ msg, const int* __restrict__ offs,
    const int* __restrict__ cnts) {
    const int lane = threadIdx.x & 63;
    const int wave = (blockIdx.x * blockDim.x + threadIdx.x) >> 6;
    const int nw = (gridDim.x * blockDim.x) >> 6;
    const int wpb = nw >> 6;
    const int r = wave / wpb;
    const int sub = wave - r * wpb;
    const int b0 = offs[r];
    const int cnt = cnts[r];
    const int ntiles = (cnt + 15) >> 4;
    const int c16 = lane & 15, kq = lane >> 4;

    const unsigned short* Wr = Ws + r * 4096 + lane * 8;
    short8 bfr[4][2];
    #pragma unroll
    for (int nb = 0; nb < 4; nb++)
        #pragma unroll
        for (int kb = 0; kb < 2; kb++)
            bfr[nb][kb] = *(const short8*)(Wr + ((nb * 2 + kb) << 9));

    int t = sub;
    if (t >= ntiles) return;

    float nnC; int slC; short8 a0, a1;
    {
        const int base = b0 + (t << 4);
        const int rem = cnt - (t << 4);
        int2 ss = ssP[base + c16];
        nnC = normP[base + c16];
        slC = ss.y;
        int sa = (c16 < rem) ? ss.x : 0;
        const unsigned short* xr = xb + sa * 64 + kq * 8;
        a0 = *(const short8*)(xr);
        a1 = *(const short8*)(xr + 32);
    }

    while (t < ntiles) {
        const int tn = t + wpb;
        float nnN = 0.f; int slN = 0; short8 a0N = a0, a1N = a1;
        if (tn < ntiles) {
            const int baseN = b0 + (tn << 4);
            const int remN = cnt - (tn << 4);
            int2 ssN = ssP[baseN + c16];
            nnN = normP[baseN + c16];
            slN = ssN.y;
            int saN = (c16 < remN) ? ssN.x : 0;
            const unsigned short* xrN = xb + saN * 64 + kq * 8;
            a0N = *(const short8*)(xrN);
            a1N = *(const short8*)(xrN + 32);
        }
        const int rem = cnt - (t << 4);
        f32x4 acc0{0.f, 0.f, 0.f, 0.f}, acc1{0.f, 0.f, 0.f, 0.f};
        f32x4 acc2{0.f, 0.f, 0.f, 0.f}, acc3{0.f, 0.f, 0.f, 0.f};
        acc0 = __builtin_amdgcn_mfma_f32_16x16x32_bf16(a0, bfr[0][0], acc0, 0, 0, 0);
        acc0 = __builtin_amdgcn_mfma_f32_16x16x32_bf16(a1, bfr[0][1], acc0, 0, 0, 0);
        acc1 = __builtin_amdgcn_mfma_f32_16x16x32_bf16(a0, bfr[1][0], acc1, 0, 0, 0);
        acc1 = __builtin_amdgcn_mfma_f32_16x16x32_bf16(a1, bfr[1][1], acc1, 0, 0, 0);
        acc2 = __builtin_amdgcn_mfma_f32_16x16x32_bf16(a0, bfr[2][0], acc2, 0, 0, 0);
        acc2 = __builtin_amdgcn_mfma_f32_16x16x32_bf16(a1, bfr[2][1], acc2, 0, 0, 0);
        acc3 = __builtin_amdgcn_mfma_f32_16x16x32_bf16(a0, bfr[3][0], acc3, 0, 0, 0);
        acc3 = __builtin_amdgcn_mfma_f32_16x16x32_bf16(a1, bfr[3][1], acc3, 0, 0, 0);
        #pragma unroll
        for (int ri = 0; ri < 4; ri++) {
            int li = kq * 4 + ri;
            bool valid = li < rem;
            float nn = shfl_f(nnC, li);
            int slot = shfl_i(slC, li);
            if (valid) {
                unsigned int p01 = (unsigned int)f2bf(acc0[ri] * nn) |
                                   ((unsigned int)f2bf(acc1[ri] * nn) << 16);
                unsigned int p23 = (unsigned int)f2bf(acc2[ri] * nn) |
                                   ((unsigned int)f2bf(acc3[ri] * nn) << 16);
                unsigned int* mp = (unsigned int*)(msg + (size_t)slot * 64);
                __builtin_nontemporal_store(p01, mp + c16);
                __builtin_nontemporal_store(p23, mp + 16 + c16);
            }
        }
        nnC = nnN; slC = slN; a0 = a0N; a1 = a1N;
        t = tn;
    }
}

__global__ void __launch_bounds__(256) edge2_mfmaA(
    const int2* __restrict__ ssP, const float* __restrict__ normP,
    const unsigned short* __restrict__ hb, const unsigned short* __restrict__ Ws,
    unsigned short* __restrict__ msg, const int* __restrict__ offs,
    const int* __restrict__ cnts) {
    const int lane = threadIdx.x & 63;
    const int wave = (blockIdx.x * blockDim.x + threadIdx.x) >> 6;
    const int nw = (gridDim.x * blockDim.x) >> 6;
    const int wpb = nw >> 6;
    const int r = wave / wpb;
    const int sub = wave - r * wpb;
    const int b0 = offs[r];
    const int cnt = cnts[r];
    const int ntiles = (cnt + 15) >> 4;
    const int c16 = lane & 15, kq = lane >> 4;

    const unsigned short* Wr = Ws + r * 2048 + lane * 8;
    short8 bfr[2][2];
    #pragma unroll
    for (int nb = 0; nb < 2; nb++)
        #pragma unroll
        for (int kb = 0; kb < 2; kb++)
            bfr[nb][kb] = *(const short8*)(Wr + ((nb * 2 + kb) << 9));

    int t = sub;
    if (t >= ntiles) return;

    float nnC; int slC; short8 a0, a1;
    {
        const int base = b0 + (t << 4);
        const int rem = cnt - (t << 4);
        int2 ss = ssP[base + c16];
        nnC = normP[base + c16];
        slC = ss.y;
        int sa = (c16 < rem) ? ss.x : 0;
        const unsigned short* xr = hb + sa * 64 + kq * 8;
        a0 = *(const short8*)(xr);
        a1 = *(const short8*)(xr + 32);
    }

    while (t < ntiles) {
        const int tn = t + wpb;
        float nnN = 0.f; int slN = 0; short8 a0N = a0, a1N = a1;
        if (tn < ntiles) {
            const int baseN = b0 + (tn << 4);
            const int remN = cnt - (tn << 4);
            int2 ssN = ssP[baseN + c16];
            nnN = normP[baseN + c16];
            slN = ssN.y;
            int saN = (c16 < remN) ? ssN.x : 0;
            const unsigned short* xrN = hb + saN * 64 + kq * 8;
            a0N = *(const short8*)(xrN);
            a1N = *(const short8*)(xrN + 32);
        }
        const int rem = cnt - (t << 4);
        f32x4 acc0{0.f, 0.f, 0.f, 0.f}, acc1{0.f, 0.f, 0.f, 0.f};
        acc0 = __builtin_amdgcn_mfma_f32_16x16x32_bf16(a0, bfr[0][0], acc0, 0, 0, 0);
        acc0 = __builtin_amdgcn_mfma_f32_16x16x32_bf16(a1, bfr[0][1], acc0, 0, 0, 0);
        acc1 = __builtin_amdgcn_mfma_f32_16x16x32_bf16(a0, bfr[1][0], acc1, 0, 0, 0);
        acc1 = __builtin_amdgcn_mfma_f32_16x16x32_bf16(a1, bfr[1][1], acc1, 0, 0, 0);
        #pragma unroll
        for (int ri = 0; ri < 4; ri++) {
            int li = kq * 4 + ri;
            bool valid = li < rem;
            float nn = shfl_f(nnC, li);
            int slot = shfl_i(slC, li);
            if (valid) {
                unsigned int p01 = (unsigned int)f2bf(acc0[ri] * nn) |
                                   ((unsigned int)f2bf(acc1[ri] * nn) << 16);
                __builtin_nontemporal_store(p01,
                    (unsigned int*)(msg + (size_t)slot * 32) + c16);
            }
        }
        nnC = nnN; slC = slN; a0 = a0N; a1 = a1N;
        t = tn;
    }
}

// ---------- segment sums (nontemporal msg reads, 4-deep ILP) ----------
__global__ void __launch_bounds__(256) segsum1(const unsigned short* __restrict__ msg,
                                               const int* __restrict__ noff,
                                               const float* __restrict__ b1,
                                               unsigned short* __restrict__ hb) {
    int v = (blockIdx.x * blockDim.x + threadIdx.x) >> 6;
    int lane = threadIdx.x & 63;
    if (v >= N_NODES) return;
    int s0 = noff[v], s1 = noff[v + 1];
    float a0 = 0.f, a1 = 0.f, a2 = 0.f, a3 = 0.f;
    int i = s0;
    for (; i + 3 < s1; i += 4) {
        a0 += bf2f(__builtin_nontemporal_load(msg + (size_t)i * 64 + lane));
        a1 += bf2f(__builtin_nontemporal_load(msg + (size_t)(i + 1) * 64 + lane));
        a2 += bf2f(__builtin_nontemporal_load(msg + (size_t)(i + 2) * 64 + lane));
        a3 += bf2f(__builtin_nontemporal_load(msg + (size_t)(i + 3) * 64 + lane));
    }
    for (; i < s1; i++)
        a0 += bf2f(__builtin_nontemporal_load(msg + (size_t)i * 64 + lane));
    float val = fmaxf((a0 + a1) + (a2 + a3) + b1[lane], 0.f);
    hb[v * 64 + lane] = f2bf(val);
}

__global__ void __launch_bounds__(256) segsum2(const unsigned short* __restrict__ msg,
                                               const int* __restrict__ noff,
                                               const float* __restrict__ b2,
                                               float* __restrict__ out) {
    int idx = blockIdx.x * blockDim.x + threadIdx.x;
    int v = idx >> 5, o = idx & 31;
    if (v >= N_NODES) return;
    int s0 = noff[v], s1 = noff[v + 1];
    float a0 = 0.f, a1 = 0.f, a2 = 0.f, a3 = 0.f;
    int i = s0;
    for (; i + 3 < s1; i += 4) {
        a0 += bf2f(__builtin_nontemporal_load(msg + (size_t)i * 32 + o));
        a1 += bf2f(__builtin_nontemporal_load(msg + (size_t)(i + 1) * 32 + o));
        a2 += bf2f(__builtin_nontemporal_load(msg + (size_t)(i + 2) * 32 + o));
        a3 += bf2f(__builtin_nontemporal_load(msg + (size_t)(i + 3) * 32 + o));
    }
    for (; i < s1; i++)
        a0 += bf2f(__builtin_nontemporal_load(msg + (size_t)i * 32 + o));
    out[v * 32 + o] = (a0 + a1) + (a2 + a3) + b2[o];
}

// =========================================================================
// PATH B: atomics fallback — used only if ws_size is too small.
// =========================================================================
__global__ void hist_kernel(const int* __restrict__ etype, int* __restrict__ counts) {
    __shared__ int lbin[N_RELS];
    for (int i = threadIdx.x; i < N_RELS; i += blockDim.x) lbin[i] = 0;
    __syncthreads();
    for (int e = blockIdx.x * blockDim.x + threadIdx.x; e < N_EDGES;
         e += gridDim.x * blockDim.x)
        atomicAdd(&lbin[etype[e]], 1);
    __syncthreads();
    for (int i = threadIdx.x; i < N_RELS; i += blockDim.x)
        if (lbin[i]) atomicAdd(&counts[i], lbin[i]);
}

__global__ void cvt_bf16_kernel(const float* __restrict__ in,
                                unsigned short* __restrict__ outp, int n4) {
    int i = blockIdx.x * blockDim.x + threadIdx.x;
    if (i < n4) {
        float4 v = ((const float4*)in)[i];
        ushort4 o;
        o.x = f2bf(v.x); o.y = f2bf(v.y); o.z = f2bf(v.z); o.w = f2bf(v.w);
        ((ushort4*)outp)[i] = o;
    }
}

__global__ void build_w_swz(const float* __restrict__ V1, const float* __restrict__ c1,
                            const float* __restrict__ V2, const float* __restrict__ c2,
                            unsigned short* __restrict__ W1s, unsigned short* __restrict__ W2s) {
    int idx = blockIdx.x * blockDim.x + threadIdx.x;
    const int n1 = N_RELS * 4096;
    const int n2 = N_RELS * 2048;
    if (idx < n1) {
        int r = idx >> 12;
        int f = idx & 4095;
        int nb = f >> 10, kb = (f >> 9) & 1, s = f & 511;
        int lane = s >> 3, j = s & 7;
        int k = 32 * kb + 8 * (lane >> 4) + j;
        int col = ((nb >> 1) << 5) + 2 * (lane & 15) + (nb & 1);
        float acc = 0.f;
        #pragma unroll
        for (int b = 0; b < N_BASES; b++)
            acc += c1[r * N_BASES + b] * V1[(b * 64 + k) * 64 + col];
        W1s[idx] = f2bf(acc);
    } else if (idx < n1 + n2) {
        int t = idx - n1;
        int r = t >> 11;
        int f = t & 2047;
        int nb = f >> 10, kb = (f >> 9) & 1, s = f & 511;
        int lane = s >> 3, j = s & 7;
        int k = 32 * kb + 8 * (lane >> 4) + j;
        int col = 2 * (lane & 15) + nb;
        float acc = 0.f;
        #pragma unroll
        for (int b = 0; b < N_BASES; b++)
            acc += c2[r * N_BASES + b] * V2[(b * 64 + k) * 32 + col];
        W2s[t] = f2bf(acc);
    }
}

__global__ void scan_kernel(const int* __restrict__ counts, int* __restrict__ offs,
                            int* __restrict__ cursor, int nbins) {
    if (threadIdx.x == 0 && blockIdx.x == 0) {
        int L = 0;
        for (int r = 0; r < nbins; r++) {
            offs[r] = L;
            cursor[r] = L;
            L += (counts[r] + 63) & ~63;
        }
        offs[nbins] = L;
    }
}

__global__ void scatter_kernel(const int* __restrict__ etype, int* __restrict__ cursor,
                               int* __restrict__ perm) {
    __shared__ int lbin[N_RELS];
    __shared__ int lbase[N_RELS];
    const int nChunks = (N_EDGES + 255) >> 8;
    for (int chunk = blockIdx.x; chunk < nChunks; chunk += gridDim.x) {
        for (int i = threadIdx.x; i < N_RELS; i += blockDim.x) lbin[i] = 0;
        __syncthreads();
        int e = chunk * 256 + threadIdx.x;
        int r = -1, lpos = 0;
        if (e < N_EDGES) {
            r = etype[e];
            lpos = atomicAdd(&lbin[r], 1);
        }
        __syncthreads();
        for (int i = threadIdx.x; i < N_RELS; i += blockDim.x)
            lbase[i] = lbin[i] ? atomicAdd(&cursor[i], lbin[i]) : 0;
        __syncthreads();
        if (e < N_EDGES) perm[lbase[r] + lpos] = e;
        __syncthreads();
    }
}

__global__ void __launch_bounds__(256) edge1_mfmaB(
    const int* __restrict__ perm, const int* __restrict__ src,
    const int* __restrict__ dst, const float* __restrict__ norm,
    const unsigned short* __restrict__ xb, const unsigned short* __restrict__ Ws,
    float* __restrict__ hout, const int* __restrict__ offs) {
    const int lane = threadIdx.x & 63;
    const int wave = (blockIdx.x * blockDim.x + threadIdx.x) >> 6;
    const int nw = (gridDim.x * blockDim.x) >> 6;
    const int wpb = nw >> 6;
    const int r = wave / wpb;
    const int sub = wave - r * wpb;
    const int b0 = offs[r], b1v = offs[r + 1];
    const int ntiles = (b1v - b0) >> 4;
    const int c16 = lane & 15, kq = lane >> 4;
    const unsigned short* Wr = Ws + r * 4096 + lane * 8;
    short8 bfr[4][2];
    #pragma unroll
    for (int nb = 0; nb < 4; nb++)
        #pragma unroll
        for (int kb = 0; kb < 2; kb++)
            bfr[nb][kb] = *(const short8*)(Wr + ((nb * 2 + kb) << 9));
    for (int t = sub; t < ntiles; t += wpb) {
        const int base = b0 + (t << 4);
        int pa = perm[base + c16];
        int sa = pa < 0 ? 0 : src[pa];
        const unsigned short* xr = xb + sa * 64 + kq * 8;
        short8 a0 = *(const short8*)(xr);
        short8 a1 = *(const short8*)(xr + 32);
        f32x4 acc0{0.f, 0.f, 0.f, 0.f}, acc1{0.f, 0.f, 0.f, 0.f};
        f32x4 acc2{0.f, 0.f, 0.f, 0.f}, acc3{0.f, 0.f, 0.f, 0.f};
        acc0 = __builtin_amdgcn_mfma_f32_16x16x32_bf16(a0, bfr[0][0], acc0, 0, 0, 0);
        acc0 = __builtin_amdgcn_mfma_f32_16x16x32_bf16(a1, bfr[0][1], acc0, 0, 0, 0);
        acc1 = __builtin_amdgcn_mfma_f32_16x16x32_bf16(a0, bfr[1][0], acc1, 0, 0, 0);
        acc1 = __builtin_amdgcn_mfma_f32_16x16x32_bf16(a1, bfr[1][1], acc1, 0, 0, 0);
        acc2 = __builtin_amdgcn_mfma_f32_16x16x32_bf16(a0, bfr[2][0], acc2, 0, 0, 0);
        acc2 = __builtin_amdgcn_mfma_f32_16x16x32_bf16(a1, bfr[2][1], acc2, 0, 0, 0);
        acc3 = __builtin_amdgcn_mfma_f32_16x16x32_bf16(a0, bfr[3][0], acc3, 0, 0, 0);
        acc3 = __builtin_amdgcn_mfma_f32_16x16x32_bf16(a1, bfr[3][1], acc3, 0, 0, 0);
        #pragma unroll
        for (int ri = 0; ri < 4; ri++) {
            int pe = perm[base + kq * 4 + ri];
            float nn = 0.f;
            int d = 0;
            if (pe >= 0) { nn = norm[pe]; d = dst[pe]; }
            float* hrow = hout + d * 64;
            unsafeAtomicAdd(hrow + 2 * c16,      acc0[ri] * nn);
            unsafeAtomicAdd(hrow + 2 * c16 + 1,  acc1[ri] * nn);
            unsafeAtomicAdd(hrow + 32 + 2 * c16, acc2[ri] * nn);
            unsafeAtomicAdd(hrow + 33 + 2 * c16, acc3[ri] * nn);
        }
    }
}

__global__ void bias_relu_bf(const float* __restrict__ h, const float* __restrict__ b,
                             unsigned short* __restrict__ hb, int n4) {
    int i = blockIdx.x * blockDim.x + threadIdx.x;
    if (i < n4) {
        float4 v = ((const float4*)h)[i];
        float4 bv = ((const float4*)b)[i & 15];
        ushort4 o;
        o.x = f2bf(fmaxf(v.x + bv.x, 0.f));
        o.y = f2bf(fmaxf(v.y + bv.y, 0.f));
        o.z = f2bf(fmaxf(v.z + bv.z, 0.f));
        o.w = f2bf(fmaxf(v.w + bv.w, 0.f));
        ((ushort4*)hb)[i] = o;
    }
}

__global__ void __launch_bounds__(256) edge2_mfmaB(
    const int* __restrict__ perm, const int* __restrict__ src,
    const int* __restrict__ dst, const float* __restrict__ norm,
    const unsigned short* __restrict__ hb, const unsigned short* __restrict__ Ws,
    float* __restrict__ out, const int* __restrict__ offs) {
    const int lane = threadIdx.x & 63;
    const int wave = (blockIdx.x * blockDim.x + threadIdx.x) >> 6;
    const int nw = (gridDim.x * blockDim.x) >> 6;
    const int wpb = nw >> 6;
    const int r = wave / wpb;
    const int sub = wave - r * wpb;
    const int b0 = offs[r], b1v = offs[r + 1];
    const int ntiles = (b1v - b0) >> 4;
    const int c16 = lane & 15, kq = lane >> 4;
    const unsigned short* Wr = Ws + r * 2048 + lane * 8;
    short8 bfr[2][2];
    #pragma unroll
    for (int nb = 0; nb < 2; nb++)
        #pragma unroll
        for (int kb = 0; kb < 2; kb++)
            bfr[nb][kb] = *(const short8*)(Wr + ((nb * 2 + kb) << 9));
    for (int t = sub; t < ntiles; t += wpb) {
        const int base = b0 + (t << 4);
        int pa = perm[base + c16];
        int sa = pa < 0 ? 0 : src[pa];
        const unsigned short* xr = hb + sa * 64 + kq * 8;
        short8 a0 = *(const short8*)(xr);
        short8 a1 = *(const short8*)(xr + 32);
        f32x4 acc0{0.f, 0.f, 0.f, 0.f}, acc1{0.f, 0.f, 0.f, 0.f};
        acc0 = __builtin_amdgcn_mfma_f32_16x16x32_bf16(a0, bfr[0][0], acc0, 0, 0, 0);
        acc0 = __builtin_amdgcn_mfma_f32_16x16x32_bf16(a1, bfr[0][1], acc0, 0, 0, 0);
        acc1 = __builtin_amdgcn_mfma_f32_16x16x32_bf16(a0, bfr[1][0], acc1, 0, 0, 0);
        acc1 = __builtin_amdgcn_mfma_f32_16x16x32_bf16(a1, bfr[1][1], acc1, 0, 0, 0);
        #pragma unroll
        for (int ri = 0; ri < 4; ri++) {
            int pe = perm[base + kq * 4 + ri];
            float nn = 0.f;
            int d = 0;
            if (pe >= 0) { nn = norm[pe]; d = dst[pe]; }
            float* orow = out + d * 32;
            unsafeAtomicAdd(orow + 2 * c16,     acc0[ri] * nn);
            unsafeAtomicAdd(orow + 2 * c16 + 1, acc1[ri] * nn);
        }
    }
}

__global__ void bias2_kernel(float* __restrict__ out, const float* __restrict__ b) {
    const int total = N_NODES * OUT_DIM;
    for (int idx = blockIdx.x * blockDim.x + threadIdx.x; idx < total;
         idx += gridDim.x * blockDim.x)
        out[idx] += b[idx & (OUT_DIM - 1)];
}

extern "C" void kernel_launch(void* const* d_in, const int* in_sizes, int n_in,
                              void* d_out, int out_size, void* d_ws, size_t ws_size,
                              hipStream_t stream) {
    const int*   src   = (const int*)d_in[0];
    const int*   dst   = (const int*)d_in[1];
    const int*   etype = (const int*)d_in[2];
    const float* norm  = (const float*)d_in[3];
    const float* emb   = (const float*)d_in[4];
    const float* V1    = (const float*)d_in[5];
    const float* c1    = (const float*)d_in[6];
    const float* b1    = (const float*)d_in[7];
    const float* V2    = (const float*)d_in[8];
    const float* c2    = (const float*)d_in[9];
    const float* b2    = (const float*)d_in[10];
    float* out = (float*)d_out;
    char* ws = (char*)d_ws;

    // ---- Path A layout (identical to round 11/13; NEED_A = 251,241,088) ----
    unsigned short* W1s = (unsigned short*)(ws);                 // @0          524,288
    unsigned short* W2s = (unsigned short*)(ws + 524288);        //             262,144
    unsigned short* xb  = (unsigned short*)(ws + 786432);        //          12,800,000
    unsigned short* hbA = (unsigned short*)(ws + 13586432);      //          12,800,000
    int2*  ssP   = (int2*)(ws + 26386432);                       //          12,832,768
    float* normP = (float*)(ws + 39219200);                      //           6,420,480
    int*   noff  = (int*)(ws + 45639680);                        //             400,128
    int*   dcnt  = (int*)(ws + 46039808);                        //             400,000
    int* counts  = (int*)(ws + 46439808);                        //                 256
    int*   offs  = (int*)(ws + 46440064);                        //                 512
    int*  cur64  = (int*)(ws + 46440576);                        //                 512
    unsigned short* msg = (unsigned short*)(ws + 46441088);      //         204,800,000
    const size_t NEED_A = 46441088ull + 204800000ull;            //     251,241,088

    // rank aliases the head of msg (dead before edge1 writes msg)
    int* rank = (int*)msg;                       // 6,400,000 B
    // scan scratch aliased into hbA (dead until segsum1)
    int* nloc = (int*)hbA;                       // 400,000 B
    int* bsum = (int*)(ws + 13586432 + 400128);  // 100 ints

    if (ws_size >= NEED_A) {
        // ================= PATH A: fused prep + merged scans =================
        (void)hipMemsetAsync(counts, 0, 256, stream);
        (void)hipMemsetAsync(dcnt, 0, 400000, stream);

        prep_fused<<<PREP_BW + PREP_HIST + PREP_CVT, 256, 0, stream>>>(
            V1, c1, V2, c2, W1s, W2s, emb, xb, etype, dst, counts, dcnt, rank);
        scan_a2<<<99, 1024, 0, stream>>>(dcnt, nloc, bsum, counts, offs, cur64);
        scan_c2<<<98, 1024, 0, stream>>>(nloc, bsum, noff);
        scatter_big<<<782, 256, 0, stream>>>(etype, src, dst, norm, rank, noff,
                                             cur64, ssP, normP);
        edge1_mfmaA<<<4096, 256, 0, stream>>>(ssP, normP, xb, W1s, msg, offs, counts);
        segsum1<<<25000, 256, 0, stream>>>(msg, noff, b1, hbA);
        edge2_mfmaA<<<4096, 256, 0, stream>>>(ssP, normP, hbA, W2s, msg, offs, counts);
        segsum2<<<12500, 256, 0, stream>>>(msg, noff, b2, out);
    } else {
        // ================= PATH B: fallback =================
        unsigned short* hbB = xb;                                // alias
        float* h    = (float*)(ws + 13586432);                   // 25,600,000
        int*   permB = (int*)(ws + 39186432);                    //  6,416,384
        int* countsB = (int*)(ws + 45602816);
        int*   offsB = (int*)(ws + 45603072);
        int* cursorB = (int*)(ws + 45603584);

        (void)hipMemsetAsync(h, 0, (size_t)N_NODES * H_DIM * 4, stream);
        (void)hipMemsetAsync(out, 0, (size_t)out_size * 4, stream);
        (void)hipMemsetAsync(countsB, 0, 256, stream);
        (void)hipMemsetAsync(permB, 0xFF, (size_t)(N_EDGES + 4096) * 4, stream);

        build_w_swz<<<1536, 256, 0, stream>>>(V1, c1, V2, c2, W1s, W2s);
        cvt_bf16_kernel<<<6250, 256, 0, stream>>>(emb, xb, (N_NODES * H_DIM) / 4);
        hist_kernel<<<1024, 256, 0, stream>>>(etype, countsB);
        scan_kernel<<<1, 64, 0, stream>>>(countsB, offsB, cursorB, N_RELS);
        scatter_kernel<<<2048, 256, 0, stream>>>(etype, cursorB, permB);
        edge1_mfmaB<<<2048, 256, 0, stream>>>(permB, src, dst, norm, xb, W1s, h, offsB);
        bias_relu_bf<<<6250, 256, 0, stream>>>(h, b1, hbB, (N_NODES * H_DIM) / 4);
        edge2_mfmaB<<<2048, 256, 0, stream>>>(permB, src, dst, norm, hbB, W2s, out, offsB);
        bias2_kernel<<<4096, 256, 0, stream>>>(out, b2);
    }
}